// Round 1
// baseline (13185.408 us; speedup 1.0000x reference)
//
#include <hip/hip_runtime.h>

#define N_NODES 100000
#define N_EDGES 1600000

// ---------------- degree histogram (int atomics) ----------------
__global__ __launch_bounds__(256) void k_degrees(const int* __restrict__ ei,
                                                 int* __restrict__ deg) {
    int e = blockIdx.x * 256 + threadIdx.x;
    int lr = blockIdx.y;                       // 0..5 = layer*3 + rel
    if (e >= N_EDGES) return;
    const int* base = ei + (size_t)lr * 2 * N_EDGES;
    int s = base[e];
    int d = base[N_EDGES + e];
    atomicAdd(&deg[(size_t)(lr * 2 + 0) * N_NODES + s], 1);
    atomicAdd(&deg[(size_t)(lr * 2 + 1) * N_NODES + d], 1);
}

// ---------------- deg -> rsqrt(clamp(deg,1)) ----------------
__global__ __launch_bounds__(256) void k_rsqrt(const int* __restrict__ deg,
                                               float* __restrict__ rs) {
    int i = blockIdx.x * 256 + threadIdx.x;
    if (i >= 12 * N_NODES) return;
    int v = deg[i];
    rs[i] = rsqrtf((float)(v < 1 ? 1 : v));
}

// ---------------- layer-1 scatter: agg[dst][128r+c] += w * x[src][c] ----------------
__global__ __launch_bounds__(256) void k_scatter1(const int* __restrict__ ei,
                                                  const float* __restrict__ x,
                                                  const float* __restrict__ rs,
                                                  float* __restrict__ agg) {
    int r = blockIdx.y;
    size_t t = (size_t)blockIdx.x * 256 + threadIdx.x;
    int lane = (int)(t & 31);                  // 32 lanes x float4 = 128 floats
    size_t e = t >> 5;
    if (e >= N_EDGES) return;
    const int* base = ei + (size_t)r * 2 * N_EDGES;   // layer 0
    int s = base[e];
    int d = base[N_EDGES + e];
    float w = rs[(size_t)(r * 2 + 0) * N_NODES + s] *
              rs[(size_t)(r * 2 + 1) * N_NODES + d];
    const float4 v = *(const float4*)(x + (size_t)s * 128 + lane * 4);
    float* o = agg + (size_t)d * 384 + r * 128 + lane * 4;
    unsafeAtomicAdd(o + 0, w * v.x);
    unsafeAtomicAdd(o + 1, w * v.y);
    unsafeAtomicAdd(o + 2, w * v.z);
    unsafeAtomicAdd(o + 3, w * v.w);
}

// ---------------- GEMM1: h = relu(agg[Nx384] @ W1[384x128] + sum_r b1[r]) ----------------
__global__ __launch_bounds__(256) void k_gemm1(const float* __restrict__ A,
                                               const float* __restrict__ B,
                                               const float* __restrict__ b1,
                                               float* __restrict__ C) {
    __shared__ float As[64][33];
    __shared__ float Bs[32][128];
    int tid = threadIdx.x;
    int m0 = blockIdx.x * 64;
    int tx = tid & 15, ty = tid >> 4;
    int c0 = tx * 8, r0 = ty * 4;
    float acc[4][8];
#pragma unroll
    for (int i = 0; i < 4; i++)
#pragma unroll
        for (int j = 0; j < 8; j++) acc[i][j] = 0.f;

    for (int k0 = 0; k0 < 384; k0 += 32) {
#pragma unroll
        for (int p = 0; p < 2; p++) {            // A tile 64x32
            int row = (tid >> 3) + p * 32;
            int col = (tid & 7) * 4;
            int m = m0 + row;
            float4 v = make_float4(0.f, 0.f, 0.f, 0.f);
            if (m < N_NODES) v = *(const float4*)(A + (size_t)m * 384 + k0 + col);
            As[row][col] = v.x; As[row][col + 1] = v.y;
            As[row][col + 2] = v.z; As[row][col + 3] = v.w;
        }
#pragma unroll
        for (int p = 0; p < 4; p++) {            // B tile 32x128
            int row = (tid >> 5) + p * 8;
            int col = (tid & 31) * 4;
            *(float4*)(&Bs[row][col]) = *(const float4*)(B + (size_t)(k0 + row) * 128 + col);
        }
        __syncthreads();
#pragma unroll
        for (int kk = 0; kk < 32; kk++) {
            float a[4];
#pragma unroll
            for (int i = 0; i < 4; i++) a[i] = As[r0 + i][kk];
            float4 bA = *(const float4*)(&Bs[kk][c0]);
            float4 bB = *(const float4*)(&Bs[kk][c0 + 4]);
            float b[8] = {bA.x, bA.y, bA.z, bA.w, bB.x, bB.y, bB.z, bB.w};
#pragma unroll
            for (int i = 0; i < 4; i++)
#pragma unroll
                for (int j = 0; j < 8; j++) acc[i][j] += a[i] * b[j];
        }
        __syncthreads();
    }
    float bsv[8];
#pragma unroll
    for (int j = 0; j < 8; j++) {
        int c = c0 + j;
        bsv[j] = b1[c] + b1[128 + c] + b1[256 + c];
    }
#pragma unroll
    for (int i = 0; i < 4; i++) {
        int m = m0 + r0 + i;
        if (m < N_NODES) {
            float o[8];
#pragma unroll
            for (int j = 0; j < 8; j++) {
                float v = acc[i][j] + bsv[j];
                o[j] = v > 0.f ? v : 0.f;
            }
            *(float4*)(C + (size_t)m * 128 + c0) = make_float4(o[0], o[1], o[2], o[3]);
            *(float4*)(C + (size_t)m * 128 + c0 + 4) = make_float4(o[4], o[5], o[6], o[7]);
        }
    }
}

// ---------------- GEMM2: hW[:, r*64+c] = h[Nx128] @ W2[r][128x64] ----------------
__global__ __launch_bounds__(256) void k_gemm2(const float* __restrict__ A,
                                               const float* __restrict__ W2,
                                               float* __restrict__ hW) {
    int r = blockIdx.y;
    const float* B = W2 + (size_t)r * 128 * 64;
    __shared__ float As[64][33];
    __shared__ float Bs[32][64];
    int tid = threadIdx.x;
    int m0 = blockIdx.x * 64;
    int tx = tid & 15, ty = tid >> 4;
    int c0 = tx * 4, r0 = ty * 4;
    float acc[4][4];
#pragma unroll
    for (int i = 0; i < 4; i++)
#pragma unroll
        for (int j = 0; j < 4; j++) acc[i][j] = 0.f;

    for (int k0 = 0; k0 < 128; k0 += 32) {
#pragma unroll
        for (int p = 0; p < 2; p++) {            // A tile 64x32
            int row = (tid >> 3) + p * 32;
            int col = (tid & 7) * 4;
            int m = m0 + row;
            float4 v = make_float4(0.f, 0.f, 0.f, 0.f);
            if (m < N_NODES) v = *(const float4*)(A + (size_t)m * 128 + k0 + col);
            As[row][col] = v.x; As[row][col + 1] = v.y;
            As[row][col + 2] = v.z; As[row][col + 3] = v.w;
        }
#pragma unroll
        for (int p = 0; p < 2; p++) {            // B tile 32x64
            int row = (tid >> 4) + p * 16;
            int col = (tid & 15) * 4;
            *(float4*)(&Bs[row][col]) = *(const float4*)(B + (size_t)(k0 + row) * 64 + col);
        }
        __syncthreads();
#pragma unroll
        for (int kk = 0; kk < 32; kk++) {
            float a[4];
#pragma unroll
            for (int i = 0; i < 4; i++) a[i] = As[r0 + i][kk];
            float4 b4 = *(const float4*)(&Bs[kk][c0]);
            float b[4] = {b4.x, b4.y, b4.z, b4.w};
#pragma unroll
            for (int i = 0; i < 4; i++)
#pragma unroll
                for (int j = 0; j < 4; j++) acc[i][j] += a[i] * b[j];
        }
        __syncthreads();
    }
#pragma unroll
    for (int i = 0; i < 4; i++) {
        int m = m0 + r0 + i;
        if (m < N_NODES) {
            *(float4*)(hW + (size_t)m * 192 + r * 64 + c0) =
                make_float4(acc[i][0], acc[i][1], acc[i][2], acc[i][3]);
        }
    }
}

// ---------------- out init with summed bias ----------------
__global__ __launch_bounds__(256) void k_outinit(const float* __restrict__ b2,
                                                 float* __restrict__ out) {
    int i = blockIdx.x * 256 + threadIdx.x;
    if (i >= N_NODES * 64) return;
    int c = i & 63;
    out[i] = b2[c] + b2[64 + c] + b2[128 + c];
}

// ---------------- layer-2 scatter: out[dst][c] += w * hW[src][64r+c] ----------------
__global__ __launch_bounds__(256) void k_scatter2(const int* __restrict__ ei,
                                                  const float* __restrict__ hW,
                                                  const float* __restrict__ rs,
                                                  float* __restrict__ out) {
    int r = blockIdx.y;
    size_t t = (size_t)blockIdx.x * 256 + threadIdx.x;
    int lane = (int)(t & 15);                  // 16 lanes x float4 = 64 floats
    size_t e = t >> 4;
    if (e >= N_EDGES) return;
    const int* base = ei + (size_t)(3 + r) * 2 * N_EDGES;  // layer 1
    int s = base[e];
    int d = base[N_EDGES + e];
    float w = rs[(size_t)((3 + r) * 2 + 0) * N_NODES + s] *
              rs[(size_t)((3 + r) * 2 + 1) * N_NODES + d];
    const float4 v = *(const float4*)(hW + (size_t)s * 192 + r * 64 + lane * 4);
    float* o = out + (size_t)d * 64 + lane * 4;
    unsafeAtomicAdd(o + 0, w * v.x);
    unsafeAtomicAdd(o + 1, w * v.y);
    unsafeAtomicAdd(o + 2, w * v.z);
    unsafeAtomicAdd(o + 3, w * v.w);
}

extern "C" void kernel_launch(void* const* d_in, const int* in_sizes, int n_in,
                              void* d_out, int out_size, void* d_ws, size_t ws_size,
                              hipStream_t stream) {
    (void)in_sizes; (void)n_in; (void)out_size; (void)ws_size;
    const float* x  = (const float*)d_in[0];
    const float* W1 = (const float*)d_in[1];
    const float* b1 = (const float*)d_in[2];
    const float* W2 = (const float*)d_in[3];
    const float* b2 = (const float*)d_in[4];
    const int*   ei = (const int*)d_in[5];
    float* out = (float*)d_out;

    char* ws = (char*)d_ws;
    // layout (bytes):
    //   deg : [0, 4.8e6)           12*N int32
    //   rs  : [4.8e6, 9.6e6)       12*N float
    //   agg : [9.6e6, 163.2e6)     N*384 float  (reused as hW: N*192 float)
    //   h   : [163.2e6, 214.4e6)   N*128 float
    int*   deg = (int*)ws;
    float* rs  = (float*)(ws + 4800000);
    float* agg = (float*)(ws + 9600000);
    float* h   = (float*)(ws + 163200000);
    float* hW  = agg;   // agg is dead after GEMM1

    hipMemsetAsync(d_ws, 0, 163200000, stream);   // zero deg + rs + agg

    k_degrees<<<dim3((N_EDGES + 255) / 256, 6), 256, 0, stream>>>(ei, deg);
    k_rsqrt<<<(12 * N_NODES + 255) / 256, 256, 0, stream>>>(deg, rs);
    k_scatter1<<<dim3((N_EDGES * 32) / 256, 3), 256, 0, stream>>>(ei, x, rs, agg);
    k_gemm1<<<(N_NODES + 63) / 64, 256, 0, stream>>>(agg, W1, b1, h);
    k_gemm2<<<dim3((N_NODES + 63) / 64, 3), 256, 0, stream>>>(h, W2, hW);
    k_outinit<<<(N_NODES * 64 + 255) / 256, 256, 0, stream>>>(b2, out);
    k_scatter2<<<dim3((N_EDGES * 16) / 256, 3), 256, 0, stream>>>(ei, hW, rs, out);
}

// Round 2
// 3044.535 us; speedup vs baseline: 4.3308x; 4.3308x over previous
//
#include <hip/hip_runtime.h>

#define N_NODES 100000
#define N_EDGES 1600000
#define NB 391   // ceil(N/256) scan blocks per (layer,rel)

// workspace layout (bytes):
//   deg    @ 0          12N int   (per layer: out r0..2 at r*N, in r0..2 at (3+r)*N)
//   rs     @ 4.8e6      12N float (same layout)
//   cursor @ 9.6e6      6N int    (post-sort: end offsets per lr)
//   incl   @ 12.0e6     6N int
//   bsum   @ 14.4e6     6*400 int
//   boff   @ 14.4096e6  6*400 int
//   sorted @ 14.4192e6  6E int    (src ids sorted by dst, per lr)
//   agg    @ 52.8192e6  N*384 float (reused: hW in cols 0..192, stride 384)
#define OFF_DEG   0ull
#define OFF_RS    4800000ull
#define OFF_CUR   9600000ull
#define OFF_INCL  12000000ull
#define OFF_BSUM  14400000ull
#define OFF_BOFF  14409600ull
#define OFF_SORT  14419200ull
#define OFF_AGG   52819200ull

// ---------------- degree histogram (int atomics) ----------------
__global__ __launch_bounds__(256) void k_degrees(const int* __restrict__ ei,
                                                 int* __restrict__ deg) {
    int e = blockIdx.x * 256 + threadIdx.x;
    int lr = blockIdx.y;
    if (e >= N_EDGES) return;
    int layer = lr / 3, r = lr % 3;
    const int* base = ei + (size_t)lr * 2 * N_EDGES;
    int s = base[e], d = base[N_EDGES + e];
    int* dl = deg + (size_t)layer * 6 * N_NODES;
    atomicAdd(dl + (size_t)r * N_NODES + s, 1);
    atomicAdd(dl + (size_t)(3 + r) * N_NODES + d, 1);
}

// ---------------- deg -> rsqrt(clamp(deg,1)) ----------------
__global__ __launch_bounds__(256) void k_rsqrt(const int* __restrict__ deg,
                                               float* __restrict__ rs) {
    int i = blockIdx.x * 256 + threadIdx.x;
    if (i >= 12 * N_NODES) return;
    int v = deg[i];
    rs[i] = rsqrtf((float)(v < 1 ? 1 : v));
}

// ---------------- scan phase 1: per-block inclusive scan of in-degrees ----------------
__global__ __launch_bounds__(256) void k_scan1(const int* __restrict__ deg,
                                               int* __restrict__ incl,
                                               int* __restrict__ bsum) {
    int lr = blockIdx.y, layer = lr / 3, r = lr % 3;
    const int* degin = deg + (size_t)layer * 6 * N_NODES + (size_t)(3 + r) * N_NODES;
    int t = threadIdx.x, i = blockIdx.x * 256 + t;
    int v = (i < N_NODES) ? degin[i] : 0;
    int lane = t & 63, wid = t >> 6;
#pragma unroll
    for (int off = 1; off < 64; off <<= 1) {
        int u = __shfl_up(v, off, 64);
        if (lane >= off) v += u;
    }
    __shared__ int wsum[4];
    if (lane == 63) wsum[wid] = v;
    __syncthreads();
    for (int w = 0; w < wid; w++) v += wsum[w];
    if (i < N_NODES) incl[(size_t)lr * N_NODES + i] = v;
    if (t == 255) bsum[lr * 400 + blockIdx.x] = v;
}

// ---------------- scan phase 2: scan the block sums ----------------
__global__ __launch_bounds__(512) void k_scan2(const int* __restrict__ bsum,
                                               int* __restrict__ boff) {
    int lr = blockIdx.x, t = threadIdx.x;
    __shared__ int sm[512];
    int v = (t < NB) ? bsum[lr * 400 + t] : 0;
    sm[t] = v;
    __syncthreads();
    for (int off = 1; off < 512; off <<= 1) {
        int add = (t >= off) ? sm[t - off] : 0;
        __syncthreads();
        sm[t] += add;
        __syncthreads();
    }
    if (t < NB) boff[lr * 400 + t] = sm[t] - v;   // exclusive
}

// ---------------- scan phase 3: cursor = exclusive offset ----------------
__global__ __launch_bounds__(256) void k_scan3(const int* __restrict__ deg,
                                               const int* __restrict__ incl,
                                               const int* __restrict__ boff,
                                               int* __restrict__ cursor) {
    int lr = blockIdx.y, layer = lr / 3, r = lr % 3;
    int i = blockIdx.x * 256 + threadIdx.x;
    if (i >= N_NODES) return;
    const int* degin = deg + (size_t)layer * 6 * N_NODES + (size_t)(3 + r) * N_NODES;
    cursor[(size_t)lr * N_NODES + i] =
        incl[(size_t)lr * N_NODES + i] - degin[i] + boff[lr * 400 + blockIdx.x];
}

// ---------------- counting-sort edges by dst ----------------
__global__ __launch_bounds__(256) void k_sort(const int* __restrict__ ei,
                                              int* __restrict__ cursor,
                                              int* __restrict__ sorted) {
    int e = blockIdx.x * 256 + threadIdx.x;
    int lr = blockIdx.y;
    if (e >= N_EDGES) return;
    const int* base = ei + (size_t)lr * 2 * N_EDGES;
    int s = base[e], d = base[N_EDGES + e];
    int slot = atomicAdd(&cursor[(size_t)lr * N_NODES + d], 1);
    sorted[(size_t)lr * N_EDGES + slot] = s;
}

// ---------------- layer-1 pull: one wave per dst, 3 rels interleaved ----------------
__global__ __launch_bounds__(256) void k_pull1(const int* __restrict__ sorted,
                                               const int* __restrict__ cursor,
                                               const int* __restrict__ deg,
                                               const float* __restrict__ rs,
                                               const float* __restrict__ x,
                                               float* __restrict__ agg) {
    int wid = threadIdx.x >> 6, lane = threadIdx.x & 63;
    int dst = blockIdx.x * 4 + wid;
    if (dst >= N_NODES) return;
    const float2* x2 = (const float2*)x;
    const int* deg0in = deg + 3 * N_NODES;
    int j0, j1, j2, n0, n1, n2;
    {
        int e0 = cursor[dst],               c0 = deg0in[dst];
        int e1 = cursor[N_NODES + dst],     c1 = deg0in[N_NODES + dst];
        int e2 = cursor[2 * N_NODES + dst], c2 = deg0in[2 * N_NODES + dst];
        j0 = e0 - c0; j1 = e1 - c1; j2 = e2 - c2;
        n0 = c0; n1 = c1; n2 = c2;
    }
    float2 a0 = make_float2(0.f, 0.f), a1 = a0, a2 = a0;
    int m = max(n0, max(n1, n2));
    for (int it = 0; it < m; ++it) {
        if (it < n0) {
            int s = sorted[j0 + it];
            float w = rs[s];
            float2 v = x2[(size_t)s * 64 + lane];
            a0.x += w * v.x; a0.y += w * v.y;
        }
        if (it < n1) {
            int s = sorted[N_EDGES + j1 + it];
            float w = rs[N_NODES + s];
            float2 v = x2[(size_t)s * 64 + lane];
            a1.x += w * v.x; a1.y += w * v.y;
        }
        if (it < n2) {
            int s = sorted[2 * N_EDGES + j2 + it];
            float w = rs[2 * N_NODES + s];
            float2 v = x2[(size_t)s * 64 + lane];
            a2.x += w * v.x; a2.y += w * v.y;
        }
    }
    float2* row = (float2*)(agg + (size_t)dst * 384);
    float w;
    w = rs[3 * N_NODES + dst]; row[lane]       = make_float2(a0.x * w, a0.y * w);
    w = rs[4 * N_NODES + dst]; row[64 + lane]  = make_float2(a1.x * w, a1.y * w);
    w = rs[5 * N_NODES + dst]; row[128 + lane] = make_float2(a2.x * w, a2.y * w);
}

// ---------------- fused GEMM: hW = relu(agg@W1 + sum b1) @ W2[r], in-place cols 0..192 ----------------
__global__ __launch_bounds__(256) void k_gemm12(const float* __restrict__ A,
                                                const float* __restrict__ W1,
                                                const float* __restrict__ b1,
                                                const float* __restrict__ W2,
                                                float* __restrict__ hW) {
    __shared__ float As[64][33];
    __shared__ float Bs[32][132];
    __shared__ float Hs[64][132];
    int tid = threadIdx.x;
    int m0 = blockIdx.x * 64;
    int tx = tid & 15, ty = tid >> 4;
    int c0 = tx * 8, r0 = ty * 4;
    float acc[4][8];
#pragma unroll
    for (int i = 0; i < 4; i++)
#pragma unroll
        for (int j = 0; j < 8; j++) acc[i][j] = 0.f;

    for (int k0 = 0; k0 < 384; k0 += 32) {
#pragma unroll
        for (int p = 0; p < 2; p++) {
            int row = (tid >> 3) + p * 32;
            int col = (tid & 7) * 4;
            int mm = m0 + row;
            float4 v = make_float4(0.f, 0.f, 0.f, 0.f);
            if (mm < N_NODES) v = *(const float4*)(A + (size_t)mm * 384 + k0 + col);
            As[row][col] = v.x; As[row][col + 1] = v.y;
            As[row][col + 2] = v.z; As[row][col + 3] = v.w;
        }
#pragma unroll
        for (int p = 0; p < 4; p++) {
            int row = (tid >> 5) + p * 8;
            int col = (tid & 31) * 4;
            *(float4*)(&Bs[row][col]) = *(const float4*)(W1 + (size_t)(k0 + row) * 128 + col);
        }
        __syncthreads();
#pragma unroll
        for (int kk = 0; kk < 32; kk++) {
            float a[4];
#pragma unroll
            for (int i = 0; i < 4; i++) a[i] = As[r0 + i][kk];
            float4 bA = *(const float4*)(&Bs[kk][c0]);
            float4 bB = *(const float4*)(&Bs[kk][c0 + 4]);
            float b[8] = {bA.x, bA.y, bA.z, bA.w, bB.x, bB.y, bB.z, bB.w};
#pragma unroll
            for (int i = 0; i < 4; i++)
#pragma unroll
                for (int j = 0; j < 8; j++) acc[i][j] += a[i] * b[j];
        }
        __syncthreads();
    }
    // bias + relu -> Hs
#pragma unroll
    for (int j = 0; j < 8; j++) {
        int c = c0 + j;
        float bs = b1[c] + b1[128 + c] + b1[256 + c];
#pragma unroll
        for (int i = 0; i < 4; i++) {
            float v = acc[i][j] + bs;
            Hs[r0 + i][c] = v > 0.f ? v : 0.f;
        }
    }
    __syncthreads();

    // stage 2: hW[:, r*64..] = Hs @ W2[r]
    int c2 = (tid & 15) * 4;
#pragma unroll
    for (int r = 0; r < 3; r++) {
        const float* Br = W2 + (size_t)r * 128 * 64;
        float acc2[4][4];
#pragma unroll
        for (int i = 0; i < 4; i++)
#pragma unroll
            for (int j = 0; j < 4; j++) acc2[i][j] = 0.f;
        for (int k0 = 0; k0 < 128; k0 += 32) {
            {
                int row = tid >> 3;          // 0..31
                int col = (tid & 7) * 8;     // 0..56
                *(float4*)(&Bs[row][col])     = *(const float4*)(Br + (size_t)(k0 + row) * 64 + col);
                *(float4*)(&Bs[row][col + 4]) = *(const float4*)(Br + (size_t)(k0 + row) * 64 + col + 4);
            }
            __syncthreads();
#pragma unroll
            for (int kk = 0; kk < 32; kk++) {
                float a[4];
#pragma unroll
                for (int i = 0; i < 4; i++) a[i] = Hs[r0 + i][k0 + kk];
                float4 b4 = *(const float4*)(&Bs[kk][c2]);
#pragma unroll
                for (int i = 0; i < 4; i++) {
                    acc2[i][0] += a[i] * b4.x;
                    acc2[i][1] += a[i] * b4.y;
                    acc2[i][2] += a[i] * b4.z;
                    acc2[i][3] += a[i] * b4.w;
                }
            }
            __syncthreads();
        }
#pragma unroll
        for (int i = 0; i < 4; i++) {
            int mm = m0 + r0 + i;
            if (mm < N_NODES)
                *(float4*)(hW + (size_t)mm * 384 + r * 64 + c2) =
                    make_float4(acc2[i][0], acc2[i][1], acc2[i][2], acc2[i][3]);
        }
    }
}

// ---------------- layer-2 pull: one wave per dst, writes out once ----------------
__global__ __launch_bounds__(256) void k_pull2(const int* __restrict__ sorted1,
                                               const int* __restrict__ cursor1,
                                               const int* __restrict__ deg1,
                                               const float* __restrict__ rs1,
                                               const float* __restrict__ hW,
                                               const float* __restrict__ b2,
                                               float* __restrict__ out) {
    int wid = threadIdx.x >> 6, lane = threadIdx.x & 63;
    int dst = blockIdx.x * 4 + wid;
    if (dst >= N_NODES) return;
    const int* deg1in = deg1 + 3 * N_NODES;
    int j0, j1, j2, n0, n1, n2;
    {
        int e0 = cursor1[dst],               c0 = deg1in[dst];
        int e1 = cursor1[N_NODES + dst],     c1 = deg1in[N_NODES + dst];
        int e2 = cursor1[2 * N_NODES + dst], c2 = deg1in[2 * N_NODES + dst];
        j0 = e0 - c0; j1 = e1 - c1; j2 = e2 - c2;
        n0 = c0; n1 = c1; n2 = c2;
    }
    float a0 = 0.f, a1 = 0.f, a2 = 0.f;
    int m = max(n0, max(n1, n2));
    for (int it = 0; it < m; ++it) {
        if (it < n0) {
            int s = sorted1[j0 + it];
            a0 += rs1[s] * hW[(size_t)s * 384 + lane];
        }
        if (it < n1) {
            int s = sorted1[N_EDGES + j1 + it];
            a1 += rs1[N_NODES + s] * hW[(size_t)s * 384 + 64 + lane];
        }
        if (it < n2) {
            int s = sorted1[2 * N_EDGES + j2 + it];
            a2 += rs1[2 * N_NODES + s] * hW[(size_t)s * 384 + 128 + lane];
        }
    }
    float o = a0 * rs1[3 * N_NODES + dst] + a1 * rs1[4 * N_NODES + dst] +
              a2 * rs1[5 * N_NODES + dst] + b2[lane] + b2[64 + lane] + b2[128 + lane];
    out[(size_t)dst * 64 + lane] = o;
}

extern "C" void kernel_launch(void* const* d_in, const int* in_sizes, int n_in,
                              void* d_out, int out_size, void* d_ws, size_t ws_size,
                              hipStream_t stream) {
    (void)in_sizes; (void)n_in; (void)out_size; (void)ws_size;
    const float* x  = (const float*)d_in[0];
    const float* W1 = (const float*)d_in[1];
    const float* b1 = (const float*)d_in[2];
    const float* W2 = (const float*)d_in[3];
    const float* b2 = (const float*)d_in[4];
    const int*   ei = (const int*)d_in[5];
    float* out = (float*)d_out;

    char* ws = (char*)d_ws;
    int*   deg    = (int*)(ws + OFF_DEG);
    float* rs     = (float*)(ws + OFF_RS);
    int*   cursor = (int*)(ws + OFF_CUR);
    int*   incl   = (int*)(ws + OFF_INCL);
    int*   bsum   = (int*)(ws + OFF_BSUM);
    int*   boff   = (int*)(ws + OFF_BOFF);
    int*   sorted = (int*)(ws + OFF_SORT);
    float* agg    = (float*)(ws + OFF_AGG);

    hipMemsetAsync(deg, 0, 4800000, stream);

    k_degrees<<<dim3(6250, 6), 256, 0, stream>>>(ei, deg);
    k_rsqrt<<<4688, 256, 0, stream>>>(deg, rs);
    k_scan1<<<dim3(NB, 6), 256, 0, stream>>>(deg, incl, bsum);
    k_scan2<<<6, 512, 0, stream>>>(bsum, boff);
    k_scan3<<<dim3(NB, 6), 256, 0, stream>>>(deg, incl, boff, cursor);
    k_sort<<<dim3(6250, 6), 256, 0, stream>>>(ei, cursor, sorted);
    k_pull1<<<25000, 256, 0, stream>>>(sorted, cursor, deg, rs, x, agg);
    k_gemm12<<<1563, 256, 0, stream>>>(agg, W1, b1, W2, agg);
    k_pull2<<<25000, 256, 0, stream>>>(sorted + 3 * (size_t)N_EDGES,
                                       cursor + 3 * (size_t)N_NODES,
                                       deg + 6 * (size_t)N_NODES,
                                       rs + 6 * (size_t)N_NODES,
                                       agg, b2, out);
}

// Round 3
// 2046.422 us; speedup vs baseline: 6.4432x; 1.4877x over previous
//
#include <hip/hip_runtime.h>

#define N_NODES 100000
#define N_EDGES 1600000
#define NBUCK 250          // buckets per (layer,rel)
#define BSZ 400            // nodes per bucket (250*400 = 100000)
#define CHUNK 8192         // edges per partition block
#define NCHUNK 196         // ceil(E/CHUNK)
#define CAP 8192           // LDS staging capacity in k_bsort

// workspace layout (bytes), total 204,018,432 (< 214.4e6 known good):
#define OFF_DEG   0ull           // 12N int: per layer, out r0..2 then in r0..2
#define OFF_GC    4800000ull     // 1500 int bucket counts (pad to 6144)
#define OFF_BB    4806144ull     // 1500 int bucket bases
#define OFF_BC    4812288ull     // 1500 int bucket cursors
#define OFF_RS    4818432ull     // 12N float
#define OFF_START 9618432ull     // 6N int CSR start offsets
#define OFF_PAIRS 12018432ull    // 6E int packed (s | dd<<17), overwritten in-place with sorted src
#define OFF_AGG   50418432ull    // N*384 float (reused: hW cols 0..192, stride 384)

// inclusive scan of a[0..255] in LDS, 256 threads
__device__ __forceinline__ void lds_scan256(int* a) {
    int t = threadIdx.x;
    for (int off = 1; off < 256; off <<= 1) {
        int v = (t >= off) ? a[t - off] : 0;
        __syncthreads();
        a[t] += v;
        __syncthreads();
    }
}

// inclusive scan of a[0..511] in LDS, 256 threads (2 slots/thread)
__device__ __forceinline__ void lds_scan512(int* a) {
    int t = threadIdx.x, i1 = t + 256;
    for (int off = 1; off < 512; off <<= 1) {
        int v0 = (t >= off) ? a[t - off] : 0;
        int v1 = (i1 >= off) ? a[i1 - off] : 0;
        __syncthreads();
        a[t] += v0;
        a[i1] += v1;
        __syncthreads();
    }
}

// ---------------- bucket histogram of dst ----------------
__global__ __launch_bounds__(256) void k_bhist(const int* __restrict__ ei,
                                               int* __restrict__ gcount) {
    int lr = blockIdx.y;
    int e0 = blockIdx.x * CHUNK;
    int n = min(CHUNK, N_EDGES - e0);
    const int* bd = ei + (size_t)lr * 2 * N_EDGES + N_EDGES + e0;
    __shared__ int lh[256];
    lh[threadIdx.x] = 0;
    __syncthreads();
    for (int i = threadIdx.x; i < n; i += 256)
        atomicAdd(&lh[bd[i] / BSZ], 1);
    __syncthreads();
    int t = threadIdx.x;
    if (t < NBUCK && lh[t]) atomicAdd(&gcount[lr * NBUCK + t], lh[t]);
}

// ---------------- scan bucket counts -> bases + cursors ----------------
__global__ __launch_bounds__(256) void k_bscan(const int* __restrict__ gcount,
                                               int* __restrict__ bbase,
                                               int* __restrict__ bcursor) {
    int lr = blockIdx.x, t = threadIdx.x;
    __shared__ int a[256];
    int v = (t < NBUCK) ? gcount[lr * NBUCK + t] : 0;
    a[t] = v;
    __syncthreads();
    lds_scan256(a);
    if (t < NBUCK) {
        int excl = a[t] - v;
        bbase[lr * NBUCK + t] = excl;
        bcursor[lr * NBUCK + t] = excl;
    }
}

// ---------------- partition edges into buckets (coalesced writes) ----------------
__global__ __launch_bounds__(256) void k_bpart(const int* __restrict__ ei,
                                               int* __restrict__ bcursor,
                                               int* __restrict__ pairs) {
    int lr = blockIdx.y;
    int e0 = blockIdx.x * CHUNK;
    int n = min(CHUNK, N_EDGES - e0);
    const int* bs = ei + (size_t)lr * 2 * N_EDGES + e0;
    const int* bd = bs + N_EDGES;
    __shared__ int lh[256];        // per-bucket counts -> inclusive scan
    __shared__ int lexcl[256];
    __shared__ int lcur[256];
    __shared__ int gb[256];        // reserved global base per bucket
    __shared__ int staged[CHUNK];  // packed values grouped by bucket
    __shared__ unsigned char stb[CHUNK];
    int t = threadIdx.x;
    lh[t] = 0;
    __syncthreads();
    for (int i = t; i < n; i += 256)
        atomicAdd(&lh[bd[i] / BSZ], 1);
    __syncthreads();
    int cnt_t = lh[t];
    __syncthreads();
    lds_scan256(lh);               // lh = inclusive
    int excl_t = lh[t] - cnt_t;
    lexcl[t] = excl_t;
    lcur[t] = excl_t;
    if (t < NBUCK) gb[t] = cnt_t ? atomicAdd(&bcursor[lr * NBUCK + t], cnt_t) : 0;
    __syncthreads();
    for (int i = t; i < n; i += 256) {
        int s = bs[i], d = bd[i];
        int b = d / BSZ;
        int dd = d - b * BSZ;
        int p = atomicAdd(&lcur[b], 1);
        staged[p] = s | (dd << 17);
        stb[p] = (unsigned char)b;
    }
    __syncthreads();
    int* outp = pairs + (size_t)lr * N_EDGES;
    for (int i = t; i < n; i += 256) {
        int b = stb[i];
        outp[gb[b] + (i - lexcl[b])] = staged[i];
    }
}

// ---------------- per-bucket counting sort (in place) + CSR start + in-degree ----------------
__global__ __launch_bounds__(256) void k_bsort(const int* __restrict__ bbase,
                                               int* __restrict__ pairs,
                                               int* __restrict__ start,
                                               int* __restrict__ deg) {
    int lr = blockIdx.y, b = blockIdx.x;
    int layer = lr / 3, r = lr % 3;
    int base = bbase[lr * NBUCK + b];
    int next = (b < NBUCK - 1) ? bbase[lr * NBUCK + b + 1] : N_EDGES;
    int cnt = next - base;
    int* reg = pairs + (size_t)lr * N_EDGES + base;
    __shared__ int staged[CAP];
    __shared__ int cnt_l[512];     // counts then inclusive scan
    __shared__ int keep[BSZ];
    __shared__ int lcur[BSZ];
    int t = threadIdx.x;
    cnt_l[t] = 0; cnt_l[t + 256] = 0;
    __syncthreads();
    for (int i = t; i < cnt; i += 256) {
        int v = reg[i];
        if (i < CAP) staged[i] = v;
        atomicAdd(&cnt_l[v >> 17], 1);
    }
    __syncthreads();
    if (t < 144) keep[t + 256] = cnt_l[t + 256];
    keep[t] = cnt_l[t];
    __syncthreads();
    lds_scan512(cnt_l);
    // write CSR start + in-degree, init cursors
    int d0 = b * BSZ;
    {
        int excl = cnt_l[t] - keep[t];
        lcur[t] = excl;
        start[(size_t)lr * N_NODES + d0 + t] = base + excl;
        deg[(size_t)layer * 6 * N_NODES + (size_t)(3 + r) * N_NODES + d0 + t] = keep[t];
        if (t < 144) {
            int t2 = t + 256;
            int excl2 = cnt_l[t2] - keep[t2];
            lcur[t2] = excl2;
            start[(size_t)lr * N_NODES + d0 + t2] = base + excl2;
            deg[(size_t)layer * 6 * N_NODES + (size_t)(3 + r) * N_NODES + d0 + t2] = keep[t2];
        }
    }
    __syncthreads();
    for (int i = t; i < cnt; i += 256) {
        int v = (i < CAP) ? staged[i] : reg[i];   // overflow path ~never taken
        int p = atomicAdd(&lcur[v >> 17], 1);
        reg[p] = v & 0x1FFFF;
    }
}

// ---------------- out-degree histogram (src atomics only) ----------------
__global__ __launch_bounds__(256) void k_degout(const int* __restrict__ ei,
                                                int* __restrict__ deg) {
    int e = blockIdx.x * 256 + threadIdx.x;
    int lr = blockIdx.y;
    if (e >= N_EDGES) return;
    int layer = lr / 3, r = lr % 3;
    int s = ei[(size_t)lr * 2 * N_EDGES + e];
    atomicAdd(deg + (size_t)layer * 6 * N_NODES + (size_t)r * N_NODES + s, 1);
}

// ---------------- deg -> rsqrt(clamp(deg,1)) ----------------
__global__ __launch_bounds__(256) void k_rsqrt(const int* __restrict__ deg,
                                               float* __restrict__ rs) {
    int i = blockIdx.x * 256 + threadIdx.x;
    if (i >= 12 * N_NODES) return;
    int v = deg[i];
    rs[i] = rsqrtf((float)(v < 1 ? 1 : v));
}

// ---------------- layer-1 pull ----------------
__global__ __launch_bounds__(256) void k_pull1(const int* __restrict__ sorted,
                                               const int* __restrict__ start,
                                               const int* __restrict__ deg,
                                               const float* __restrict__ rs,
                                               const float* __restrict__ x,
                                               float* __restrict__ agg) {
    int wid = threadIdx.x >> 6, lane = threadIdx.x & 63;
    int dst = blockIdx.x * 4 + wid;
    if (dst >= N_NODES) return;
    const float2* x2 = (const float2*)x;
    const int* deg0in = deg + 3 * N_NODES;
    int j0 = start[dst],               n0 = deg0in[dst];
    int j1 = start[N_NODES + dst],     n1 = deg0in[N_NODES + dst];
    int j2 = start[2 * N_NODES + dst], n2 = deg0in[2 * N_NODES + dst];
    float2 a0 = make_float2(0.f, 0.f), a1 = a0, a2 = a0;
    int m = max(n0, max(n1, n2));
    for (int it = 0; it < m; ++it) {
        if (it < n0) {
            int s = sorted[j0 + it];
            float w = rs[s];
            float2 v = x2[(size_t)s * 64 + lane];
            a0.x += w * v.x; a0.y += w * v.y;
        }
        if (it < n1) {
            int s = sorted[N_EDGES + j1 + it];
            float w = rs[N_NODES + s];
            float2 v = x2[(size_t)s * 64 + lane];
            a1.x += w * v.x; a1.y += w * v.y;
        }
        if (it < n2) {
            int s = sorted[2 * N_EDGES + j2 + it];
            float w = rs[2 * N_NODES + s];
            float2 v = x2[(size_t)s * 64 + lane];
            a2.x += w * v.x; a2.y += w * v.y;
        }
    }
    float2* row = (float2*)(agg + (size_t)dst * 384);
    float w;
    w = rs[3 * N_NODES + dst]; row[lane]       = make_float2(a0.x * w, a0.y * w);
    w = rs[4 * N_NODES + dst]; row[64 + lane]  = make_float2(a1.x * w, a1.y * w);
    w = rs[5 * N_NODES + dst]; row[128 + lane] = make_float2(a2.x * w, a2.y * w);
}

// ---------------- fused GEMM: hW = relu(agg@W1 + sum b1) @ W2[r] ----------------
__global__ __launch_bounds__(256) void k_gemm12(const float* __restrict__ A,
                                                const float* __restrict__ W1,
                                                const float* __restrict__ b1,
                                                const float* __restrict__ W2,
                                                float* __restrict__ hW) {
    __shared__ float As[64][33];
    __shared__ float Bs[32][132];
    __shared__ float Hs[64][132];
    int tid = threadIdx.x;
    int m0 = blockIdx.x * 64;
    int tx = tid & 15, ty = tid >> 4;
    int c0 = tx * 8, r0 = ty * 4;
    float acc[4][8];
#pragma unroll
    for (int i = 0; i < 4; i++)
#pragma unroll
        for (int j = 0; j < 8; j++) acc[i][j] = 0.f;

    for (int k0 = 0; k0 < 384; k0 += 32) {
#pragma unroll
        for (int p = 0; p < 2; p++) {
            int row = (tid >> 3) + p * 32;
            int col = (tid & 7) * 4;
            int mm = m0 + row;
            float4 v = make_float4(0.f, 0.f, 0.f, 0.f);
            if (mm < N_NODES) v = *(const float4*)(A + (size_t)mm * 384 + k0 + col);
            As[row][col] = v.x; As[row][col + 1] = v.y;
            As[row][col + 2] = v.z; As[row][col + 3] = v.w;
        }
#pragma unroll
        for (int p = 0; p < 4; p++) {
            int row = (tid >> 5) + p * 8;
            int col = (tid & 31) * 4;
            *(float4*)(&Bs[row][col]) = *(const float4*)(W1 + (size_t)(k0 + row) * 128 + col);
        }
        __syncthreads();
#pragma unroll
        for (int kk = 0; kk < 32; kk++) {
            float a[4];
#pragma unroll
            for (int i = 0; i < 4; i++) a[i] = As[r0 + i][kk];
            float4 bA = *(const float4*)(&Bs[kk][c0]);
            float4 bB = *(const float4*)(&Bs[kk][c0 + 4]);
            float b[8] = {bA.x, bA.y, bA.z, bA.w, bB.x, bB.y, bB.z, bB.w};
#pragma unroll
            for (int i = 0; i < 4; i++)
#pragma unroll
                for (int j = 0; j < 8; j++) acc[i][j] += a[i] * b[j];
        }
        __syncthreads();
    }
#pragma unroll
    for (int j = 0; j < 8; j++) {
        int c = c0 + j;
        float bs = b1[c] + b1[128 + c] + b1[256 + c];
#pragma unroll
        for (int i = 0; i < 4; i++) {
            float v = acc[i][j] + bs;
            Hs[r0 + i][c] = v > 0.f ? v : 0.f;
        }
    }
    __syncthreads();

    int c2 = (tid & 15) * 4;
#pragma unroll
    for (int r = 0; r < 3; r++) {
        const float* Br = W2 + (size_t)r * 128 * 64;
        float acc2[4][4];
#pragma unroll
        for (int i = 0; i < 4; i++)
#pragma unroll
            for (int j = 0; j < 4; j++) acc2[i][j] = 0.f;
        for (int k0 = 0; k0 < 128; k0 += 32) {
            {
                int row = tid >> 3;
                int col = (tid & 7) * 8;
                *(float4*)(&Bs[row][col])     = *(const float4*)(Br + (size_t)(k0 + row) * 64 + col);
                *(float4*)(&Bs[row][col + 4]) = *(const float4*)(Br + (size_t)(k0 + row) * 64 + col + 4);
            }
            __syncthreads();
#pragma unroll
            for (int kk = 0; kk < 32; kk++) {
                float a[4];
#pragma unroll
                for (int i = 0; i < 4; i++) a[i] = Hs[r0 + i][k0 + kk];
                float4 b4 = *(const float4*)(&Bs[kk][c2]);
#pragma unroll
                for (int i = 0; i < 4; i++) {
                    acc2[i][0] += a[i] * b4.x;
                    acc2[i][1] += a[i] * b4.y;
                    acc2[i][2] += a[i] * b4.z;
                    acc2[i][3] += a[i] * b4.w;
                }
            }
            __syncthreads();
        }
#pragma unroll
        for (int i = 0; i < 4; i++) {
            int mm = m0 + r0 + i;
            if (mm < N_NODES)
                *(float4*)(hW + (size_t)mm * 384 + r * 64 + c2) =
                    make_float4(acc2[i][0], acc2[i][1], acc2[i][2], acc2[i][3]);
        }
    }
}

// ---------------- layer-2 pull ----------------
__global__ __launch_bounds__(256) void k_pull2(const int* __restrict__ sorted1,
                                               const int* __restrict__ start1,
                                               const int* __restrict__ deg1,
                                               const float* __restrict__ rs1,
                                               const float* __restrict__ hW,
                                               const float* __restrict__ b2,
                                               float* __restrict__ out) {
    int wid = threadIdx.x >> 6, lane = threadIdx.x & 63;
    int dst = blockIdx.x * 4 + wid;
    if (dst >= N_NODES) return;
    const int* deg1in = deg1 + 3 * N_NODES;
    int j0 = start1[dst],               n0 = deg1in[dst];
    int j1 = start1[N_NODES + dst],     n1 = deg1in[N_NODES + dst];
    int j2 = start1[2 * N_NODES + dst], n2 = deg1in[2 * N_NODES + dst];
    float a0 = 0.f, a1 = 0.f, a2 = 0.f;
    int m = max(n0, max(n1, n2));
    for (int it = 0; it < m; ++it) {
        if (it < n0) {
            int s = sorted1[j0 + it];
            a0 += rs1[s] * hW[(size_t)s * 384 + lane];
        }
        if (it < n1) {
            int s = sorted1[N_EDGES + j1 + it];
            a1 += rs1[N_NODES + s] * hW[(size_t)s * 384 + 64 + lane];
        }
        if (it < n2) {
            int s = sorted1[2 * N_EDGES + j2 + it];
            a2 += rs1[2 * N_NODES + s] * hW[(size_t)s * 384 + 128 + lane];
        }
    }
    float o = a0 * rs1[3 * N_NODES + dst] + a1 * rs1[4 * N_NODES + dst] +
              a2 * rs1[5 * N_NODES + dst] + b2[lane] + b2[64 + lane] + b2[128 + lane];
    out[(size_t)dst * 64 + lane] = o;
}

extern "C" void kernel_launch(void* const* d_in, const int* in_sizes, int n_in,
                              void* d_out, int out_size, void* d_ws, size_t ws_size,
                              hipStream_t stream) {
    (void)in_sizes; (void)n_in; (void)out_size; (void)ws_size;
    const float* x  = (const float*)d_in[0];
    const float* W1 = (const float*)d_in[1];
    const float* b1 = (const float*)d_in[2];
    const float* W2 = (const float*)d_in[3];
    const float* b2 = (const float*)d_in[4];
    const int*   ei = (const int*)d_in[5];
    float* out = (float*)d_out;

    char* ws = (char*)d_ws;
    int*   deg    = (int*)(ws + OFF_DEG);
    int*   gcount = (int*)(ws + OFF_GC);
    int*   bbase  = (int*)(ws + OFF_BB);
    int*   bcursor= (int*)(ws + OFF_BC);
    float* rs     = (float*)(ws + OFF_RS);
    int*   start  = (int*)(ws + OFF_START);
    int*   pairs  = (int*)(ws + OFF_PAIRS);
    float* agg    = (float*)(ws + OFF_AGG);

    // zero: deg (out-deg atomics; in-deg fully overwritten) + gcount
    hipMemsetAsync(ws, 0, OFF_BB, stream);

    k_bhist<<<dim3(NCHUNK, 6), 256, 0, stream>>>(ei, gcount);
    k_bscan<<<6, 256, 0, stream>>>(gcount, bbase, bcursor);
    k_bpart<<<dim3(NCHUNK, 6), 256, 0, stream>>>(ei, bcursor, pairs);
    k_bsort<<<dim3(NBUCK, 6), 256, 0, stream>>>(bbase, pairs, start, deg);
    k_degout<<<dim3(6250, 6), 256, 0, stream>>>(ei, deg);
    k_rsqrt<<<4688, 256, 0, stream>>>(deg, rs);
    k_pull1<<<25000, 256, 0, stream>>>(pairs, start, deg, rs, x, agg);
    k_gemm12<<<1563, 256, 0, stream>>>(agg, W1, b1, W2, agg);
    k_pull2<<<25000, 256, 0, stream>>>(pairs + 3 * (size_t)N_EDGES,
                                       start + 3 * (size_t)N_NODES,
                                       deg + 6 * (size_t)N_NODES,
                                       rs + 6 * (size_t)N_NODES,
                                       agg, b2, out);
}

// Round 4
// 1731.830 us; speedup vs baseline: 7.6136x; 1.1817x over previous
//
#include <hip/hip_runtime.h>

#define N_NODES 100000
#define N_EDGES 1600000
#define NBUCK 250          // buckets per (layer,rel)
#define BSZ 400            // nodes per bucket (250*400 = 100000)
#define CHUNK 8192         // edges per partition block
#define NCHUNK 196         // ceil(E/CHUNK)
#define CAP 8192           // LDS staging capacity in k_bsort
#define MTILES 6250        // N_NODES / 16

typedef _Float16 half8 __attribute__((ext_vector_type(8)));
typedef _Float16 half2v __attribute__((ext_vector_type(2)));
typedef float floatx4 __attribute__((ext_vector_type(4)));

// workspace layout (bytes), total ~191.4 MB (< 204 MB known good):
#define OFF_DEG   0ull           // 12N int
#define OFF_GC    4800000ull     // 1500 int (pad 6144)
#define OFF_BB    4806144ull
#define OFF_BC    4812288ull
#define OFF_RS    4818432ull     // 12N float
#define OFF_START 9618432ull     // 6N int
#define OFF_PAIRS 12018432ull    // 6E int
#define OFF_XH    50418432ull    // N*128 fp16 (row-major)
#define OFF_W1F   76018432ull    // 96*512 fp16 (frag order)
#define OFF_W2F   76116736ull    // 48*512 fp16 (frag order)
#define OFF_AGG   76165888ull    // N*384 fp16, A-fragment layout
#define OFF_HW    152965888ull   // N*192 fp16, row-major

__device__ __forceinline__ void lds_scan256(int* a) {
    int t = threadIdx.x;
    for (int off = 1; off < 256; off <<= 1) {
        int v = (t >= off) ? a[t - off] : 0;
        __syncthreads();
        a[t] += v;
        __syncthreads();
    }
}

__device__ __forceinline__ void lds_scan512(int* a) {
    int t = threadIdx.x, i1 = t + 256;
    for (int off = 1; off < 512; off <<= 1) {
        int v0 = (t >= off) ? a[t - off] : 0;
        int v1 = (i1 >= off) ? a[i1 - off] : 0;
        __syncthreads();
        a[t] += v0;
        a[i1] += v1;
        __syncthreads();
    }
}

// ---------------- bucket histogram of dst ----------------
__global__ __launch_bounds__(256) void k_bhist(const int* __restrict__ ei,
                                               int* __restrict__ gcount) {
    int lr = blockIdx.y;
    int e0 = blockIdx.x * CHUNK;
    int n = min(CHUNK, N_EDGES - e0);
    const int* bd = ei + (size_t)lr * 2 * N_EDGES + N_EDGES + e0;
    __shared__ int lh[256];
    lh[threadIdx.x] = 0;
    __syncthreads();
    for (int i = threadIdx.x; i < n; i += 256)
        atomicAdd(&lh[bd[i] / BSZ], 1);
    __syncthreads();
    int t = threadIdx.x;
    if (t < NBUCK && lh[t]) atomicAdd(&gcount[lr * NBUCK + t], lh[t]);
}

// ---------------- scan bucket counts ----------------
__global__ __launch_bounds__(256) void k_bscan(const int* __restrict__ gcount,
                                               int* __restrict__ bbase,
                                               int* __restrict__ bcursor) {
    int lr = blockIdx.x, t = threadIdx.x;
    __shared__ int a[256];
    int v = (t < NBUCK) ? gcount[lr * NBUCK + t] : 0;
    a[t] = v;
    __syncthreads();
    lds_scan256(a);
    if (t < NBUCK) {
        int excl = a[t] - v;
        bbase[lr * NBUCK + t] = excl;
        bcursor[lr * NBUCK + t] = excl;
    }
}

// ---------------- partition edges into buckets ----------------
__global__ __launch_bounds__(256) void k_bpart(const int* __restrict__ ei,
                                               int* __restrict__ bcursor,
                                               int* __restrict__ pairs) {
    int lr = blockIdx.y;
    int e0 = blockIdx.x * CHUNK;
    int n = min(CHUNK, N_EDGES - e0);
    const int* bs = ei + (size_t)lr * 2 * N_EDGES + e0;
    const int* bd = bs + N_EDGES;
    __shared__ int lh[256];
    __shared__ int lexcl[256];
    __shared__ int lcur[256];
    __shared__ int gb[256];
    __shared__ int staged[CHUNK];
    __shared__ unsigned char stb[CHUNK];
    int t = threadIdx.x;
    lh[t] = 0;
    __syncthreads();
    for (int i = t; i < n; i += 256)
        atomicAdd(&lh[bd[i] / BSZ], 1);
    __syncthreads();
    int cnt_t = lh[t];
    __syncthreads();
    lds_scan256(lh);
    int excl_t = lh[t] - cnt_t;
    lexcl[t] = excl_t;
    lcur[t] = excl_t;
    if (t < NBUCK) gb[t] = cnt_t ? atomicAdd(&bcursor[lr * NBUCK + t], cnt_t) : 0;
    __syncthreads();
    for (int i = t; i < n; i += 256) {
        int s = bs[i], d = bd[i];
        int b = d / BSZ;
        int dd = d - b * BSZ;
        int p = atomicAdd(&lcur[b], 1);
        staged[p] = s | (dd << 17);
        stb[p] = (unsigned char)b;
    }
    __syncthreads();
    int* outp = pairs + (size_t)lr * N_EDGES;
    for (int i = t; i < n; i += 256) {
        int b = stb[i];
        outp[gb[b] + (i - lexcl[b])] = staged[i];
    }
}

// ---------------- per-bucket counting sort + CSR + in-degree ----------------
__global__ __launch_bounds__(256) void k_bsort(const int* __restrict__ bbase,
                                               int* __restrict__ pairs,
                                               int* __restrict__ start,
                                               int* __restrict__ deg) {
    int lr = blockIdx.y, b = blockIdx.x;
    int layer = lr / 3, r = lr % 3;
    int base = bbase[lr * NBUCK + b];
    int next = (b < NBUCK - 1) ? bbase[lr * NBUCK + b + 1] : N_EDGES;
    int cnt = next - base;
    int* reg = pairs + (size_t)lr * N_EDGES + base;
    __shared__ int staged[CAP];
    __shared__ int cnt_l[512];
    __shared__ int keep[BSZ];
    __shared__ int lcur[BSZ];
    int t = threadIdx.x;
    cnt_l[t] = 0; cnt_l[t + 256] = 0;
    __syncthreads();
    for (int i = t; i < cnt; i += 256) {
        int v = reg[i];
        if (i < CAP) staged[i] = v;
        atomicAdd(&cnt_l[v >> 17], 1);
    }
    __syncthreads();
    if (t < 144) keep[t + 256] = cnt_l[t + 256];
    keep[t] = cnt_l[t];
    __syncthreads();
    lds_scan512(cnt_l);
    int d0 = b * BSZ;
    {
        int excl = cnt_l[t] - keep[t];
        lcur[t] = excl;
        start[(size_t)lr * N_NODES + d0 + t] = base + excl;
        deg[(size_t)layer * 6 * N_NODES + (size_t)(3 + r) * N_NODES + d0 + t] = keep[t];
        if (t < 144) {
            int t2 = t + 256;
            int excl2 = cnt_l[t2] - keep[t2];
            lcur[t2] = excl2;
            start[(size_t)lr * N_NODES + d0 + t2] = base + excl2;
            deg[(size_t)layer * 6 * N_NODES + (size_t)(3 + r) * N_NODES + d0 + t2] = keep[t2];
        }
    }
    __syncthreads();
    for (int i = t; i < cnt; i += 256) {
        int v = (i < CAP) ? staged[i] : reg[i];
        int p = atomicAdd(&lcur[v >> 17], 1);
        reg[p] = v & 0x1FFFF;
    }
}

// ---------------- out-degree ----------------
__global__ __launch_bounds__(256) void k_degout(const int* __restrict__ ei,
                                                int* __restrict__ deg) {
    int e = blockIdx.x * 256 + threadIdx.x;
    int lr = blockIdx.y;
    if (e >= N_EDGES) return;
    int layer = lr / 3, r = lr % 3;
    int s = ei[(size_t)lr * 2 * N_EDGES + e];
    atomicAdd(deg + (size_t)layer * 6 * N_NODES + (size_t)r * N_NODES + s, 1);
}

__global__ __launch_bounds__(256) void k_rsqrt(const int* __restrict__ deg,
                                               float* __restrict__ rs) {
    int i = blockIdx.x * 256 + threadIdx.x;
    if (i >= 12 * N_NODES) return;
    int v = deg[i];
    rs[i] = rsqrtf((float)(v < 1 ? 1 : v));
}

// ---------------- x -> fp16 (row-major) ----------------
__global__ __launch_bounds__(256) void k_cvt_x(const float* __restrict__ x,
                                               _Float16* __restrict__ xh) {
    int i = blockIdx.x * 256 + threadIdx.x;   // over N*64 float2s
    if (i >= N_NODES * 64) return;
    float2 v = ((const float2*)x)[i];
    half2v h; h.x = (_Float16)v.x; h.y = (_Float16)v.y;
    ((half2v*)xh)[i] = h;
}

// ---------------- W1/W2 -> fp16 fragment order ----------------
// W1f[g*512 + L*8 + j] = W1[kc*32+(L>>4)*8+j][nt*16+(L&15)], g=kc*8+nt
// W2f[g*512 + L*8 + j] = W2[r][kc*32+(L>>4)*8+j][c], g=kc*12+nt2, n=nt2*16+(L&15), r=n>>6, c=n&63
__global__ __launch_bounds__(256) void k_repack(const float* __restrict__ W1,
                                                const float* __restrict__ W2,
                                                _Float16* __restrict__ W1f,
                                                _Float16* __restrict__ W2f) {
    int i = blockIdx.x * 256 + threadIdx.x;
    if (i < 96 * 512) {
        int g = i >> 9, rem = i & 511, L = rem >> 3, j = rem & 7;
        int kc = g >> 3, nt = g & 7;
        int k = kc * 32 + (L >> 4) * 8 + j;
        int n = nt * 16 + (L & 15);
        W1f[i] = (_Float16)W1[k * 128 + n];
    } else if (i < 96 * 512 + 48 * 512) {
        int ii = i - 96 * 512;
        int g = ii >> 9, rem = ii & 511, L = rem >> 3, j = rem & 7;
        int kc = g / 12, nt = g % 12;
        int k = kc * 32 + (L >> 4) * 8 + j;
        int n = nt * 16 + (L & 15);
        int r = n >> 6, c = n & 63;
        W2f[ii] = (_Float16)W2[r * 8192 + k * 64 + c];
    }
}

// ---------------- layer-1 pull: gather fp16 x, write agg in A-frag fp16 layout ----------------
// agg halves index: ((m>>4)*48 + (k>>3))*128 + (m&15)*8 + (k&7)
__global__ __launch_bounds__(256) void k_pull1(const int* __restrict__ sorted,
                                               const int* __restrict__ start,
                                               const int* __restrict__ deg,
                                               const float* __restrict__ rs,
                                               const _Float16* __restrict__ xh,
                                               _Float16* __restrict__ agg) {
    int wid = threadIdx.x >> 6, lane = threadIdx.x & 63;
    int dst = blockIdx.x * 4 + wid;
    if (dst >= N_NODES) return;
    const half2v* x2 = (const half2v*)xh;
    const int* deg0in = deg + 3 * N_NODES;
    int j0 = start[dst],               n0 = deg0in[dst];
    int j1 = start[N_NODES + dst],     n1 = deg0in[N_NODES + dst];
    int j2 = start[2 * N_NODES + dst], n2 = deg0in[2 * N_NODES + dst];
    float2 a0 = make_float2(0.f, 0.f), a1 = a0, a2 = a0;
    int m = max(n0, max(n1, n2));
    for (int it = 0; it < m; ++it) {
        if (it < n0) {
            int s = sorted[j0 + it];
            float w = rs[s];
            half2v v = x2[(size_t)s * 64 + lane];
            a0.x += w * (float)v.x; a0.y += w * (float)v.y;
        }
        if (it < n1) {
            int s = sorted[N_EDGES + j1 + it];
            float w = rs[N_NODES + s];
            half2v v = x2[(size_t)s * 64 + lane];
            a1.x += w * (float)v.x; a1.y += w * (float)v.y;
        }
        if (it < n2) {
            int s = sorted[2 * N_EDGES + j2 + it];
            float w = rs[2 * N_NODES + s];
            half2v v = x2[(size_t)s * 64 + lane];
            a2.x += w * (float)v.x; a2.y += w * (float)v.y;
        }
    }
    size_t mbase = (size_t)(dst >> 4) * 48 * 128;
    int moff = (dst & 15) * 8;
#pragma unroll
    for (int r = 0; r < 3; r++) {
        float2 a = (r == 0) ? a0 : (r == 1) ? a1 : a2;
        float w = rs[(size_t)(3 + r) * N_NODES + dst];
        int k = r * 128 + 2 * lane;
        size_t idx = mbase + (size_t)(k >> 3) * 128 + moff + (k & 7);
        half2v h; h.x = (_Float16)(a.x * w); h.y = (_Float16)(a.y * w);
        *(half2v*)(agg + idx) = h;
    }
}

// ---------------- fused MFMA GEMM: hW = relu(agg@W1 + sum b1) @ W2[r] ----------------
__global__ __launch_bounds__(256) void k_gemm12(const _Float16* __restrict__ Af,
                                                const _Float16* __restrict__ W1f,
                                                const float* __restrict__ b1,
                                                const _Float16* __restrict__ W2f,
                                                _Float16* __restrict__ hW) {
    __shared__ _Float16 Hs[4][2048];   // 16x128 per wave, A-frag layout
    int tid = threadIdx.x;
    int w = tid >> 6, L = tid & 63;
    int mt = blockIdx.x * 4 + w;
    if (mt >= MTILES) return;
    const half8* Aw  = (const half8*)Af + (size_t)mt * 768 / 8;   // 768 halves per (mt,kc=0) row? no:
    // h8 index = mt*768/8? A halves per mtile = 48*128 = 6144 -> h8 = 768. frag idx = mt*768 + kc*64 + L
    const half8* A8  = (const half8*)Af;
    const half8* B1  = (const half8*)W1f;
    const half8* B2  = (const half8*)W2f;
    (void)Aw;

    floatx4 acc[8];
#pragma unroll
    for (int nt = 0; nt < 8; nt++) acc[nt] = (floatx4)(0.f);
#pragma unroll
    for (int kc = 0; kc < 12; kc++) {
        half8 a = A8[(size_t)mt * 768 + kc * 64 + L];
#pragma unroll
        for (int nt = 0; nt < 8; nt++) {
            half8 b = B1[(kc * 8 + nt) * 64 + L];
            acc[nt] = __builtin_amdgcn_mfma_f32_16x16x32_f16(a, b, acc[nt], 0, 0, 0);
        }
    }
    // bias + relu -> Hs (A-frag layout over n as the "k" dim)
    int cl = L & 15, rw = L >> 4;
#pragma unroll
    for (int nt = 0; nt < 8; nt++) {
        int n = nt * 16 + cl;
        float bs = b1[n] + b1[128 + n] + b1[256 + n];
#pragma unroll
        for (int j = 0; j < 4; j++) {
            int mm = rw * 4 + j;
            float v = acc[nt][j] + bs;
            v = v > 0.f ? v : 0.f;
            Hs[w][(n >> 3) * 128 + mm * 8 + (n & 7)] = (_Float16)v;
        }
    }
    __syncthreads();   // intra-wave only, but cheap insurance for LDS ordering

    const half8* H8 = (const half8*)(&Hs[w][0]);
    floatx4 acc2[12];
#pragma unroll
    for (int nt = 0; nt < 12; nt++) acc2[nt] = (floatx4)(0.f);
#pragma unroll
    for (int kc = 0; kc < 4; kc++) {
        half8 a = H8[kc * 64 + L];
#pragma unroll
        for (int nt = 0; nt < 12; nt++) {
            half8 b = B2[(kc * 12 + nt) * 64 + L];
            acc2[nt] = __builtin_amdgcn_mfma_f32_16x16x32_f16(a, b, acc2[nt], 0, 0, 0);
        }
    }
#pragma unroll
    for (int nt = 0; nt < 12; nt++) {
        int n = nt * 16 + cl;
#pragma unroll
        for (int j = 0; j < 4; j++) {
            int mm = mt * 16 + rw * 4 + j;
            hW[(size_t)mm * 192 + n] = (_Float16)acc2[nt][j];
        }
    }
}

// ---------------- layer-2 pull: gather fp16 hW rows ----------------
__global__ __launch_bounds__(256) void k_pull2(const int* __restrict__ sorted1,
                                               const int* __restrict__ start1,
                                               const int* __restrict__ deg1,
                                               const float* __restrict__ rs1,
                                               const _Float16* __restrict__ hW,
                                               const float* __restrict__ b2,
                                               float* __restrict__ out) {
    int wid = threadIdx.x >> 6, lane = threadIdx.x & 63;
    int dst = blockIdx.x * 4 + wid;
    if (dst >= N_NODES) return;
    const int* deg1in = deg1 + 3 * N_NODES;
    int j0 = start1[dst],               n0 = deg1in[dst];
    int j1 = start1[N_NODES + dst],     n1 = deg1in[N_NODES + dst];
    int j2 = start1[2 * N_NODES + dst], n2 = deg1in[2 * N_NODES + dst];
    float a0 = 0.f, a1 = 0.f, a2 = 0.f;
    int m = max(n0, max(n1, n2));
    for (int it = 0; it < m; ++it) {
        if (it < n0) {
            int s = sorted1[j0 + it];
            a0 += rs1[s] * (float)hW[(size_t)s * 192 + lane];
        }
        if (it < n1) {
            int s = sorted1[N_EDGES + j1 + it];
            a1 += rs1[N_NODES + s] * (float)hW[(size_t)s * 192 + 64 + lane];
        }
        if (it < n2) {
            int s = sorted1[2 * N_EDGES + j2 + it];
            a2 += rs1[2 * N_NODES + s] * (float)hW[(size_t)s * 192 + 128 + lane];
        }
    }
    float o = a0 * rs1[3 * N_NODES + dst] + a1 * rs1[4 * N_NODES + dst] +
              a2 * rs1[5 * N_NODES + dst] + b2[lane] + b2[64 + lane] + b2[128 + lane];
    out[(size_t)dst * 64 + lane] = o;
}

extern "C" void kernel_launch(void* const* d_in, const int* in_sizes, int n_in,
                              void* d_out, int out_size, void* d_ws, size_t ws_size,
                              hipStream_t stream) {
    (void)in_sizes; (void)n_in; (void)out_size; (void)ws_size;
    const float* x  = (const float*)d_in[0];
    const float* W1 = (const float*)d_in[1];
    const float* b1 = (const float*)d_in[2];
    const float* W2 = (const float*)d_in[3];
    const float* b2 = (const float*)d_in[4];
    const int*   ei = (const int*)d_in[5];
    float* out = (float*)d_out;

    char* ws = (char*)d_ws;
    int*      deg    = (int*)(ws + OFF_DEG);
    int*      gcount = (int*)(ws + OFF_GC);
    int*      bbase  = (int*)(ws + OFF_BB);
    int*      bcursor= (int*)(ws + OFF_BC);
    float*    rs     = (float*)(ws + OFF_RS);
    int*      start  = (int*)(ws + OFF_START);
    int*      pairs  = (int*)(ws + OFF_PAIRS);
    _Float16* xh     = (_Float16*)(ws + OFF_XH);
    _Float16* W1f    = (_Float16*)(ws + OFF_W1F);
    _Float16* W2f    = (_Float16*)(ws + OFF_W2F);
    _Float16* agg    = (_Float16*)(ws + OFF_AGG);
    _Float16* hW     = (_Float16*)(ws + OFF_HW);

    hipMemsetAsync(ws, 0, OFF_BB, stream);   // deg + gcount

    k_cvt_x<<<25000, 256, 0, stream>>>(x, xh);
    k_repack<<<288, 256, 0, stream>>>(W1, W2, W1f, W2f);
    k_bhist<<<dim3(NCHUNK, 6), 256, 0, stream>>>(ei, gcount);
    k_bscan<<<6, 256, 0, stream>>>(gcount, bbase, bcursor);
    k_bpart<<<dim3(NCHUNK, 6), 256, 0, stream>>>(ei, bcursor, pairs);
    k_bsort<<<dim3(NBUCK, 6), 256, 0, stream>>>(bbase, pairs, start, deg);
    k_degout<<<dim3(6250, 6), 256, 0, stream>>>(ei, deg);
    k_rsqrt<<<4688, 256, 0, stream>>>(deg, rs);
    k_pull1<<<25000, 256, 0, stream>>>(pairs, start, deg, rs, xh, agg);
    k_gemm12<<<(MTILES + 3) / 4, 256, 0, stream>>>(agg, W1f, b1, W2f, hW);
    k_pull2<<<25000, 256, 0, stream>>>(pairs + 3 * (size_t)N_EDGES,
                                       start + 3 * (size_t)N_NODES,
                                       deg + 6 * (size_t)N_NODES,
                                       rs + 6 * (size_t)N_NODES,
                                       hW, b2, out);
}

// Round 5
// 1085.595 us; speedup vs baseline: 12.1458x; 1.5953x over previous
//
#include <hip/hip_runtime.h>

#define N_NODES 100000
#define N_EDGES 1600000
#define NBUCK 250          // buckets per (layer,rel)
#define BSZ 400            // nodes per bucket (250*400 = 100000)
#define CHUNK 8192         // edges per partition block
#define NCHUNK 196         // ceil(E/CHUNK)
#define CAP 8192           // LDS staging capacity in k_bsort
#define MTILES 6250        // N_NODES / 16

typedef _Float16 half8 __attribute__((ext_vector_type(8)));
typedef _Float16 half2v __attribute__((ext_vector_type(2)));
typedef float floatx4 __attribute__((ext_vector_type(4)));

// workspace layout (bytes), total ~191.4 MB:
#define OFF_DEG   0ull           // 12N int
#define OFF_GC    4800000ull     // 1500 int (pad 6144)
#define OFF_BB    4806144ull
#define OFF_BC    4812288ull
#define OFF_RS    4818432ull     // 12N float
#define OFF_START 9618432ull     // 6N int
#define OFF_PAIRS 12018432ull    // 6E int
#define OFF_XH    50418432ull    // N*128 fp16 (row-major)
#define OFF_W1F   76018432ull    // 96*512 fp16 (frag order)
#define OFF_W2F   76116736ull    // 48*512 fp16 (frag order)
#define OFF_AGG   76165888ull    // N*384 fp16, A-fragment layout
#define OFF_HW    152965888ull   // N*192 fp16, row-major (pre-scaled by rs_out layer1)

__device__ __forceinline__ void lds_scan256(int* a) {
    int t = threadIdx.x;
    for (int off = 1; off < 256; off <<= 1) {
        int v = (t >= off) ? a[t - off] : 0;
        __syncthreads();
        a[t] += v;
        __syncthreads();
    }
}

__device__ __forceinline__ void lds_scan512(int* a) {
    int t = threadIdx.x, i1 = t + 256;
    for (int off = 1; off < 512; off <<= 1) {
        int v0 = (t >= off) ? a[t - off] : 0;
        int v1 = (i1 >= off) ? a[i1 - off] : 0;
        __syncthreads();
        a[t] += v0;
        a[i1] += v1;
        __syncthreads();
    }
}

// ---------------- bucket histogram of dst ----------------
__global__ __launch_bounds__(256) void k_bhist(const int* __restrict__ ei,
                                               int* __restrict__ gcount) {
    int lr = blockIdx.y;
    int e0 = blockIdx.x * CHUNK;
    int n = min(CHUNK, N_EDGES - e0);
    const int* bd = ei + (size_t)lr * 2 * N_EDGES + N_EDGES + e0;
    __shared__ int lh[256];
    lh[threadIdx.x] = 0;
    __syncthreads();
    for (int i = threadIdx.x; i < n; i += 256)
        atomicAdd(&lh[bd[i] / BSZ], 1);
    __syncthreads();
    int t = threadIdx.x;
    if (t < NBUCK && lh[t]) atomicAdd(&gcount[lr * NBUCK + t], lh[t]);
}

// ---------------- scan bucket counts ----------------
__global__ __launch_bounds__(256) void k_bscan(const int* __restrict__ gcount,
                                               int* __restrict__ bbase,
                                               int* __restrict__ bcursor) {
    int lr = blockIdx.x, t = threadIdx.x;
    __shared__ int a[256];
    int v = (t < NBUCK) ? gcount[lr * NBUCK + t] : 0;
    a[t] = v;
    __syncthreads();
    lds_scan256(a);
    if (t < NBUCK) {
        int excl = a[t] - v;
        bbase[lr * NBUCK + t] = excl;
        bcursor[lr * NBUCK + t] = excl;
    }
}

// ---------------- partition edges into buckets ----------------
__global__ __launch_bounds__(256) void k_bpart(const int* __restrict__ ei,
                                               int* __restrict__ bcursor,
                                               int* __restrict__ pairs) {
    int lr = blockIdx.y;
    int e0 = blockIdx.x * CHUNK;
    int n = min(CHUNK, N_EDGES - e0);
    const int* bs = ei + (size_t)lr * 2 * N_EDGES + e0;
    const int* bd = bs + N_EDGES;
    __shared__ int lh[256];
    __shared__ int lexcl[256];
    __shared__ int lcur[256];
    __shared__ int gb[256];
    __shared__ int staged[CHUNK];
    __shared__ unsigned char stb[CHUNK];
    int t = threadIdx.x;
    lh[t] = 0;
    __syncthreads();
    for (int i = t; i < n; i += 256)
        atomicAdd(&lh[bd[i] / BSZ], 1);
    __syncthreads();
    int cnt_t = lh[t];
    __syncthreads();
    lds_scan256(lh);
    int excl_t = lh[t] - cnt_t;
    lexcl[t] = excl_t;
    lcur[t] = excl_t;
    if (t < NBUCK) gb[t] = cnt_t ? atomicAdd(&bcursor[lr * NBUCK + t], cnt_t) : 0;
    __syncthreads();
    for (int i = t; i < n; i += 256) {
        int s = bs[i], d = bd[i];
        int b = d / BSZ;
        int dd = d - b * BSZ;
        int p = atomicAdd(&lcur[b], 1);
        staged[p] = s | (dd << 17);
        stb[p] = (unsigned char)b;
    }
    __syncthreads();
    int* outp = pairs + (size_t)lr * N_EDGES;
    for (int i = t; i < n; i += 256) {
        int b = stb[i];
        outp[gb[b] + (i - lexcl[b])] = staged[i];
    }
}

// ---------------- per-bucket counting sort + CSR + in-degree ----------------
__global__ __launch_bounds__(256) void k_bsort(const int* __restrict__ bbase,
                                               int* __restrict__ pairs,
                                               int* __restrict__ start,
                                               int* __restrict__ deg) {
    int lr = blockIdx.y, b = blockIdx.x;
    int layer = lr / 3, r = lr % 3;
    int base = bbase[lr * NBUCK + b];
    int next = (b < NBUCK - 1) ? bbase[lr * NBUCK + b + 1] : N_EDGES;
    int cnt = next - base;
    int* reg = pairs + (size_t)lr * N_EDGES + base;
    __shared__ int staged[CAP];
    __shared__ int cnt_l[512];
    __shared__ int keep[BSZ];
    __shared__ int lcur[BSZ];
    int t = threadIdx.x;
    cnt_l[t] = 0; cnt_l[t + 256] = 0;
    __syncthreads();
    for (int i = t; i < cnt; i += 256) {
        int v = reg[i];
        if (i < CAP) staged[i] = v;
        atomicAdd(&cnt_l[v >> 17], 1);
    }
    __syncthreads();
    if (t < 144) keep[t + 256] = cnt_l[t + 256];
    keep[t] = cnt_l[t];
    __syncthreads();
    lds_scan512(cnt_l);
    int d0 = b * BSZ;
    {
        int excl = cnt_l[t] - keep[t];
        lcur[t] = excl;
        start[(size_t)lr * N_NODES + d0 + t] = base + excl;
        deg[(size_t)layer * 6 * N_NODES + (size_t)(3 + r) * N_NODES + d0 + t] = keep[t];
        if (t < 144) {
            int t2 = t + 256;
            int excl2 = cnt_l[t2] - keep[t2];
            lcur[t2] = excl2;
            start[(size_t)lr * N_NODES + d0 + t2] = base + excl2;
            deg[(size_t)layer * 6 * N_NODES + (size_t)(3 + r) * N_NODES + d0 + t2] = keep[t2];
        }
    }
    __syncthreads();
    for (int i = t; i < cnt; i += 256) {
        int v = (i < CAP) ? staged[i] : reg[i];
        int p = atomicAdd(&lcur[v >> 17], 1);
        reg[p] = v & 0x1FFFF;
    }
}

// ---------------- out-degree ----------------
__global__ __launch_bounds__(256) void k_degout(const int* __restrict__ ei,
                                                int* __restrict__ deg) {
    int e = blockIdx.x * 256 + threadIdx.x;
    int lr = blockIdx.y;
    if (e >= N_EDGES) return;
    int layer = lr / 3, r = lr % 3;
    int s = ei[(size_t)lr * 2 * N_EDGES + e];
    atomicAdd(deg + (size_t)layer * 6 * N_NODES + (size_t)r * N_NODES + s, 1);
}

__global__ __launch_bounds__(256) void k_rsqrt(const int* __restrict__ deg,
                                               float* __restrict__ rs) {
    int i = blockIdx.x * 256 + threadIdx.x;
    if (i >= 12 * N_NODES) return;
    int v = deg[i];
    rs[i] = rsqrtf((float)(v < 1 ? 1 : v));
}

// ---------------- x -> fp16 ----------------
__global__ __launch_bounds__(256) void k_cvt_x(const float* __restrict__ x,
                                               _Float16* __restrict__ xh) {
    int i = blockIdx.x * 256 + threadIdx.x;
    if (i >= N_NODES * 64) return;
    float2 v = ((const float2*)x)[i];
    half2v h; h.x = (_Float16)v.x; h.y = (_Float16)v.y;
    ((half2v*)xh)[i] = h;
}

// ---------------- W1/W2 -> fp16 fragment order ----------------
__global__ __launch_bounds__(256) void k_repack(const float* __restrict__ W1,
                                                const float* __restrict__ W2,
                                                _Float16* __restrict__ W1f,
                                                _Float16* __restrict__ W2f) {
    int i = blockIdx.x * 256 + threadIdx.x;
    if (i < 96 * 512) {
        int g = i >> 9, rem = i & 511, L = rem >> 3, j = rem & 7;
        int kc = g >> 3, nt = g & 7;
        int k = kc * 32 + (L >> 4) * 8 + j;
        int n = nt * 16 + (L & 15);
        W1f[i] = (_Float16)W1[k * 128 + n];
    } else if (i < 96 * 512 + 48 * 512) {
        int ii = i - 96 * 512;
        int g = ii >> 9, rem = ii & 511, L = rem >> 3, j = rem & 7;
        int kc = g / 12, nt = g % 12;
        int k = kc * 32 + (L >> 4) * 8 + j;
        int n = nt * 16 + (L & 15);
        int r = n >> 6, c = n & 63;
        W2f[ii] = (_Float16)W2[r * 8192 + k * 64 + c];
    }
}

// ---------------- per-relation gather accumulate (chunked shfl-broadcast, unroll-8) ----------------
__device__ __forceinline__ void accum_rel1(const int* __restrict__ sorted, int j, int n,
                                           const float* __restrict__ rsrow,
                                           const half2v* __restrict__ x2,
                                           int lane, float2& acc) {
    for (int base = 0; base < n; base += 64) {
        int c = n - base; if (c > 64) c = 64;
        int s_l = (lane < c) ? sorted[j + base + lane] : 0;
        float w_l = (lane < c) ? rsrow[s_l] : 0.f;
        int q = 0;
        for (; q + 8 <= c; q += 8) {
            int ss[8]; float ww[8]; half2v vv[8];
#pragma unroll
            for (int u = 0; u < 8; u++) { ss[u] = __shfl(s_l, q + u); ww[u] = __shfl(w_l, q + u); }
#pragma unroll
            for (int u = 0; u < 8; u++) vv[u] = x2[(size_t)ss[u] * 64 + lane];
#pragma unroll
            for (int u = 0; u < 8; u++) {
                acc.x += ww[u] * (float)vv[u].x;
                acc.y += ww[u] * (float)vv[u].y;
            }
        }
        for (; q < c; q++) {
            int s = __shfl(s_l, q); float w = __shfl(w_l, q);
            half2v v = x2[(size_t)s * 64 + lane];
            acc.x += w * (float)v.x; acc.y += w * (float)v.y;
        }
    }
}

// ---------------- layer-1 pull ----------------
__global__ __launch_bounds__(256) void k_pull1(const int* __restrict__ sorted,
                                               const int* __restrict__ start,
                                               const int* __restrict__ deg,
                                               const float* __restrict__ rs,
                                               const _Float16* __restrict__ xh,
                                               _Float16* __restrict__ agg) {
    int wid = threadIdx.x >> 6, lane = threadIdx.x & 63;
    int dst = blockIdx.x * 4 + wid;
    if (dst >= N_NODES) return;
    const half2v* x2 = (const half2v*)xh;
    const int* deg0in = deg + 3 * N_NODES;
    float2 a0 = make_float2(0.f, 0.f), a1 = a0, a2 = a0;
    accum_rel1(sorted, start[dst], deg0in[dst], rs, x2, lane, a0);
    accum_rel1(sorted + N_EDGES, start[N_NODES + dst], deg0in[N_NODES + dst],
               rs + N_NODES, x2, lane, a1);
    accum_rel1(sorted + 2 * N_EDGES, start[2 * N_NODES + dst], deg0in[2 * N_NODES + dst],
               rs + 2 * N_NODES, x2, lane, a2);
    size_t mbase = (size_t)(dst >> 4) * 48 * 128;
    int moff = (dst & 15) * 8;
#pragma unroll
    for (int r = 0; r < 3; r++) {
        float2 a = (r == 0) ? a0 : (r == 1) ? a1 : a2;
        float w = rs[(size_t)(3 + r) * N_NODES + dst];
        int k = r * 128 + 2 * lane;
        size_t idx = mbase + (size_t)(k >> 3) * 128 + moff + (k & 7);
        half2v h; h.x = (_Float16)(a.x * w); h.y = (_Float16)(a.y * w);
        *(half2v*)(agg + idx) = h;
    }
}

// ---------------- fused MFMA GEMM + rs_out(layer1) fold into hW ----------------
__global__ __launch_bounds__(256) void k_gemm12(const _Float16* __restrict__ Af,
                                                const _Float16* __restrict__ W1f,
                                                const float* __restrict__ b1,
                                                const _Float16* __restrict__ W2f,
                                                const float* __restrict__ rs1out,
                                                _Float16* __restrict__ hW) {
    __shared__ _Float16 Hs[4][2048];
    int tid = threadIdx.x;
    int w = tid >> 6, L = tid & 63;
    int mt = blockIdx.x * 4 + w;
    if (mt >= MTILES) return;
    const half8* A8 = (const half8*)Af;
    const half8* B1 = (const half8*)W1f;
    const half8* B2 = (const half8*)W2f;

    floatx4 acc[8];
#pragma unroll
    for (int nt = 0; nt < 8; nt++) acc[nt] = (floatx4)(0.f);
#pragma unroll
    for (int kc = 0; kc < 12; kc++) {
        half8 a = A8[(size_t)mt * 768 + kc * 64 + L];
#pragma unroll
        for (int nt = 0; nt < 8; nt++) {
            half8 b = B1[(kc * 8 + nt) * 64 + L];
            acc[nt] = __builtin_amdgcn_mfma_f32_16x16x32_f16(a, b, acc[nt], 0, 0, 0);
        }
    }
    int cl = L & 15, rw = L >> 4;
#pragma unroll
    for (int nt = 0; nt < 8; nt++) {
        int n = nt * 16 + cl;
        float bs = b1[n] + b1[128 + n] + b1[256 + n];
#pragma unroll
        for (int j = 0; j < 4; j++) {
            int mm = rw * 4 + j;
            float v = acc[nt][j] + bs;
            v = v > 0.f ? v : 0.f;
            Hs[w][(n >> 3) * 128 + mm * 8 + (n & 7)] = (_Float16)v;
        }
    }
    __syncthreads();

    const half8* H8 = (const half8*)(&Hs[w][0]);
    floatx4 acc2[12];
#pragma unroll
    for (int nt = 0; nt < 12; nt++) acc2[nt] = (floatx4)(0.f);
#pragma unroll
    for (int kc = 0; kc < 4; kc++) {
        half8 a = H8[kc * 64 + L];
#pragma unroll
        for (int nt = 0; nt < 12; nt++) {
            half8 b = B2[(kc * 12 + nt) * 64 + L];
            acc2[nt] = __builtin_amdgcn_mfma_f32_16x16x32_f16(a, b, acc2[nt], 0, 0, 0);
        }
    }
#pragma unroll
    for (int j = 0; j < 4; j++) {
        int mm = mt * 16 + rw * 4 + j;
        float wr[3] = {rs1out[mm], rs1out[N_NODES + mm], rs1out[2 * N_NODES + mm]};
#pragma unroll
        for (int nt = 0; nt < 12; nt++) {
            int n = nt * 16 + cl;
            hW[(size_t)mm * 192 + n] = (_Float16)(acc2[nt][j] * wr[nt >> 2]);
        }
    }
}

// ---------------- layer-2 per-relation gather (pre-scaled hW, no weight lookup) ----------------
__device__ __forceinline__ void accum_rel2(const int* __restrict__ sorted, int j, int n,
                                           const _Float16* __restrict__ hWr,
                                           int lane, float& acc) {
    for (int base = 0; base < n; base += 64) {
        int c = n - base; if (c > 64) c = 64;
        int s_l = (lane < c) ? sorted[j + base + lane] : 0;
        int q = 0;
        for (; q + 8 <= c; q += 8) {
            int ss[8]; _Float16 vv[8];
#pragma unroll
            for (int u = 0; u < 8; u++) ss[u] = __shfl(s_l, q + u);
#pragma unroll
            for (int u = 0; u < 8; u++) vv[u] = hWr[(size_t)ss[u] * 192 + lane];
#pragma unroll
            for (int u = 0; u < 8; u++) acc += (float)vv[u];
        }
        for (; q < c; q++) {
            int s = __shfl(s_l, q);
            acc += (float)hWr[(size_t)s * 192 + lane];
        }
    }
}

// ---------------- layer-2 pull ----------------
__global__ __launch_bounds__(256) void k_pull2(const int* __restrict__ sorted1,
                                               const int* __restrict__ start1,
                                               const int* __restrict__ deg1,
                                               const float* __restrict__ rs1,
                                               const _Float16* __restrict__ hW,
                                               const float* __restrict__ b2,
                                               float* __restrict__ out) {
    int wid = threadIdx.x >> 6, lane = threadIdx.x & 63;
    int dst = blockIdx.x * 4 + wid;
    if (dst >= N_NODES) return;
    const int* deg1in = deg1 + 3 * N_NODES;
    float a0 = 0.f, a1 = 0.f, a2 = 0.f;
    accum_rel2(sorted1, start1[dst], deg1in[dst], hW, lane, a0);
    accum_rel2(sorted1 + N_EDGES, start1[N_NODES + dst], deg1in[N_NODES + dst],
               hW + 64, lane, a1);
    accum_rel2(sorted1 + 2 * N_EDGES, start1[2 * N_NODES + dst], deg1in[2 * N_NODES + dst],
               hW + 128, lane, a2);
    float o = a0 * rs1[3 * N_NODES + dst] + a1 * rs1[4 * N_NODES + dst] +
              a2 * rs1[5 * N_NODES + dst] + b2[lane] + b2[64 + lane] + b2[128 + lane];
    out[(size_t)dst * 64 + lane] = o;
}

extern "C" void kernel_launch(void* const* d_in, const int* in_sizes, int n_in,
                              void* d_out, int out_size, void* d_ws, size_t ws_size,
                              hipStream_t stream) {
    (void)in_sizes; (void)n_in; (void)out_size; (void)ws_size;
    const float* x  = (const float*)d_in[0];
    const float* W1 = (const float*)d_in[1];
    const float* b1 = (const float*)d_in[2];
    const float* W2 = (const float*)d_in[3];
    const float* b2 = (const float*)d_in[4];
    const int*   ei = (const int*)d_in[5];
    float* out = (float*)d_out;

    char* ws = (char*)d_ws;
    int*      deg    = (int*)(ws + OFF_DEG);
    int*      gcount = (int*)(ws + OFF_GC);
    int*      bbase  = (int*)(ws + OFF_BB);
    int*      bcursor= (int*)(ws + OFF_BC);
    float*    rs     = (float*)(ws + OFF_RS);
    int*      start  = (int*)(ws + OFF_START);
    int*      pairs  = (int*)(ws + OFF_PAIRS);
    _Float16* xh     = (_Float16*)(ws + OFF_XH);
    _Float16* W1f    = (_Float16*)(ws + OFF_W1F);
    _Float16* W2f    = (_Float16*)(ws + OFF_W2F);
    _Float16* agg    = (_Float16*)(ws + OFF_AGG);
    _Float16* hW     = (_Float16*)(ws + OFF_HW);

    hipMemsetAsync(ws, 0, OFF_BB, stream);   // deg + gcount

    k_cvt_x<<<25000, 256, 0, stream>>>(x, xh);
    k_repack<<<288, 256, 0, stream>>>(W1, W2, W1f, W2f);
    k_bhist<<<dim3(NCHUNK, 6), 256, 0, stream>>>(ei, gcount);
    k_bscan<<<6, 256, 0, stream>>>(gcount, bbase, bcursor);
    k_bpart<<<dim3(NCHUNK, 6), 256, 0, stream>>>(ei, bcursor, pairs);
    k_bsort<<<dim3(NBUCK, 6), 256, 0, stream>>>(bbase, pairs, start, deg);
    k_degout<<<dim3(6250, 6), 256, 0, stream>>>(ei, deg);
    k_rsqrt<<<4688, 256, 0, stream>>>(deg, rs);
    k_pull1<<<25000, 256, 0, stream>>>(pairs, start, deg, rs, xh, agg);
    k_gemm12<<<(MTILES + 3) / 4, 256, 0, stream>>>(agg, W1f, b1, W2f,
                                                   rs + 6 * (size_t)N_NODES, hW);
    k_pull2<<<25000, 256, 0, stream>>>(pairs + 3 * (size_t)N_EDGES,
                                       start + 3 * (size_t)N_NODES,
                                       deg + 6 * (size_t)N_NODES,
                                       rs + 6 * (size_t)N_NODES,
                                       hW, b2, out);
}

// Round 6
// 779.739 us; speedup vs baseline: 16.9100x; 1.3923x over previous
//
#include <hip/hip_runtime.h>

#define N_NODES 100000
#define N_EDGES 1600000
#define NBUCK 250          // buckets per (layer,rel)
#define BSZ 400            // nodes per bucket (250*400 = 100000)
#define CHUNK 8192         // edges per partition block
#define NCHUNK 196         // ceil(E/CHUNK)
#define CAP 8192           // LDS staging capacity in k_bsort
#define MTILES 6250        // N_NODES / 16

typedef _Float16 half8 __attribute__((ext_vector_type(8)));
typedef _Float16 half2v __attribute__((ext_vector_type(2)));
typedef float floatx4 __attribute__((ext_vector_type(4)));

// workspace layout (bytes), total ~191.4 MB:
#define OFF_DEG   0ull           // 12N int: per layer, out r0..2 then in r0..2
#define OFF_GC    4800000ull     // 1500 int (pad 6144) dst-bucket counts
#define OFF_BB    4806144ull     // dst bucket bases
#define OFF_BC    4812288ull     // dst bucket cursors
#define OFF_RS    4818432ull     // 12N float
#define OFF_START 9618432ull     // 6N int
#define OFF_PAIRS 12018432ull    // 6E int
#define OFF_XH    50418432ull    // N*128 fp16 (row-major)
#define OFF_W1F   76018432ull    // 96*512 fp16 (frag order)
#define OFF_W2F   76116736ull    // 48*512 fp16 (frag order)
#define OFF_AGG   76165888ull    // N*384 fp16, A-frag layout; head reused as src-count scratch
#define OFF_HW    152965888ull   // N*192 fp16, row-major (pre-scaled by rs_out layer1)

// src-counting scratch aliased into agg region (dead until k_pull1):
#define OFF_DDS   OFF_AGG                    // 6E short = 19.2 MB
#define OFF_GCS   (OFF_AGG + 19200000ull)    // 1500 int (pad 6144)
#define OFF_BBS   (OFF_AGG + 19206144ull)    // 1500 int
#define OFF_BCS   (OFF_AGG + 19212288ull)    // 1500 int

__device__ __forceinline__ void lds_scan256(int* a) {
    int t = threadIdx.x;
    for (int off = 1; off < 256; off <<= 1) {
        int v = (t >= off) ? a[t - off] : 0;
        __syncthreads();
        a[t] += v;
        __syncthreads();
    }
}

__device__ __forceinline__ void lds_scan512(int* a) {
    int t = threadIdx.x, i1 = t + 256;
    for (int off = 1; off < 512; off <<= 1) {
        int v0 = (t >= off) ? a[t - off] : 0;
        int v1 = (i1 >= off) ? a[i1 - off] : 0;
        __syncthreads();
        a[t] += v0;
        a[i1] += v1;
        __syncthreads();
    }
}

// ---------------- fused bucket histograms of src AND dst ----------------
__global__ __launch_bounds__(256) void k_bhist2(const int* __restrict__ ei,
                                                int* __restrict__ gcount_d,
                                                int* __restrict__ gcount_s) {
    int lr = blockIdx.y;
    int e0 = blockIdx.x * CHUNK;
    int n = min(CHUNK, N_EDGES - e0);
    const int* bs = ei + (size_t)lr * 2 * N_EDGES + e0;
    const int* bd = bs + N_EDGES;
    __shared__ int lhs[256];
    __shared__ int lhd[256];
    int t = threadIdx.x;
    lhs[t] = 0; lhd[t] = 0;
    __syncthreads();
    for (int i = t; i < n; i += 256) {
        atomicAdd(&lhs[bs[i] / BSZ], 1);
        atomicAdd(&lhd[bd[i] / BSZ], 1);
    }
    __syncthreads();
    if (t < NBUCK) {
        if (lhd[t]) atomicAdd(&gcount_d[lr * NBUCK + t], lhd[t]);
        if (lhs[t]) atomicAdd(&gcount_s[lr * NBUCK + t], lhs[t]);
    }
}

// ---------------- scan bucket counts ----------------
__global__ __launch_bounds__(256) void k_bscan(const int* __restrict__ gcount,
                                               int* __restrict__ bbase,
                                               int* __restrict__ bcursor) {
    int lr = blockIdx.x, t = threadIdx.x;
    __shared__ int a[256];
    int v = (t < NBUCK) ? gcount[lr * NBUCK + t] : 0;
    a[t] = v;
    __syncthreads();
    lds_scan256(a);
    if (t < NBUCK) {
        int excl = a[t] - v;
        bbase[lr * NBUCK + t] = excl;
        bcursor[lr * NBUCK + t] = excl;
    }
}

// ---------------- partition edges into dst buckets (payload src|dd<<17) ----------------
__global__ __launch_bounds__(256) void k_bpart(const int* __restrict__ ei,
                                               int* __restrict__ bcursor,
                                               int* __restrict__ pairs) {
    int lr = blockIdx.y;
    int e0 = blockIdx.x * CHUNK;
    int n = min(CHUNK, N_EDGES - e0);
    const int* bs = ei + (size_t)lr * 2 * N_EDGES + e0;
    const int* bd = bs + N_EDGES;
    __shared__ int lh[256];
    __shared__ int lexcl[256];
    __shared__ int lcur[256];
    __shared__ int gb[256];
    __shared__ int staged[CHUNK];
    __shared__ unsigned char stb[CHUNK];
    int t = threadIdx.x;
    lh[t] = 0;
    __syncthreads();
    for (int i = t; i < n; i += 256)
        atomicAdd(&lh[bd[i] / BSZ], 1);
    __syncthreads();
    int cnt_t = lh[t];
    __syncthreads();
    lds_scan256(lh);
    int excl_t = lh[t] - cnt_t;
    lexcl[t] = excl_t;
    lcur[t] = excl_t;
    if (t < NBUCK) gb[t] = cnt_t ? atomicAdd(&bcursor[lr * NBUCK + t], cnt_t) : 0;
    __syncthreads();
    for (int i = t; i < n; i += 256) {
        int s = bs[i], d = bd[i];
        int b = d / BSZ;
        int dd = d - b * BSZ;
        int p = atomicAdd(&lcur[b], 1);
        staged[p] = s | (dd << 17);
        stb[p] = (unsigned char)b;
    }
    __syncthreads();
    int* outp = pairs + (size_t)lr * N_EDGES;
    for (int i = t; i < n; i += 256) {
        int b = stb[i];
        outp[gb[b] + (i - lexcl[b])] = staged[i];
    }
}

// ---------------- partition src into buckets (payload = 9-bit in-bucket offset) ----------------
__global__ __launch_bounds__(256) void k_bpart_s(const int* __restrict__ ei,
                                                 int* __restrict__ bcursor_s,
                                                 short* __restrict__ dds) {
    int lr = blockIdx.y;
    int e0 = blockIdx.x * CHUNK;
    int n = min(CHUNK, N_EDGES - e0);
    const int* bs = ei + (size_t)lr * 2 * N_EDGES + e0;
    __shared__ int lh[256];
    __shared__ int lexcl[256];
    __shared__ int lcur[256];
    __shared__ int gb[256];
    __shared__ short staged[CHUNK];
    __shared__ unsigned char stb[CHUNK];
    int t = threadIdx.x;
    lh[t] = 0;
    __syncthreads();
    for (int i = t; i < n; i += 256)
        atomicAdd(&lh[bs[i] / BSZ], 1);
    __syncthreads();
    int cnt_t = lh[t];
    __syncthreads();
    lds_scan256(lh);
    int excl_t = lh[t] - cnt_t;
    lexcl[t] = excl_t;
    lcur[t] = excl_t;
    if (t < NBUCK) gb[t] = cnt_t ? atomicAdd(&bcursor_s[lr * NBUCK + t], cnt_t) : 0;
    __syncthreads();
    for (int i = t; i < n; i += 256) {
        int s = bs[i];
        int b = s / BSZ;
        int p = atomicAdd(&lcur[b], 1);
        staged[p] = (short)(s - b * BSZ);
        stb[p] = (unsigned char)b;
    }
    __syncthreads();
    short* outp = dds + (size_t)lr * N_EDGES;
    for (int i = t; i < n; i += 256) {
        int b = stb[i];
        outp[gb[b] + (i - lexcl[b])] = staged[i];
    }
}

// ---------------- per-bucket src count -> out-degree (coalesced writes, no atomics) ----------------
__global__ __launch_bounds__(256) void k_bcount_s(const int* __restrict__ bbase_s,
                                                  const short* __restrict__ dds,
                                                  int* __restrict__ deg) {
    int lr = blockIdx.y, b = blockIdx.x;
    int layer = lr / 3, r = lr % 3;
    int base = bbase_s[lr * NBUCK + b];
    int next = (b < NBUCK - 1) ? bbase_s[lr * NBUCK + b + 1] : N_EDGES;
    int cnt = next - base;
    const short* reg = dds + (size_t)lr * N_EDGES + base;
    __shared__ int h[BSZ];
    int t = threadIdx.x;
    h[t] = 0;
    if (t < BSZ - 256) h[t + 256] = 0;
    __syncthreads();
    for (int i = t; i < cnt; i += 256)
        atomicAdd(&h[reg[i]], 1);
    __syncthreads();
    int* degout = deg + (size_t)layer * 6 * N_NODES + (size_t)r * N_NODES + b * BSZ;
    degout[t] = h[t];
    if (t < BSZ - 256) degout[t + 256] = h[t + 256];
}

// ---------------- per-bucket counting sort + CSR + in-degree ----------------
__global__ __launch_bounds__(256) void k_bsort(const int* __restrict__ bbase,
                                               int* __restrict__ pairs,
                                               int* __restrict__ start,
                                               int* __restrict__ deg) {
    int lr = blockIdx.y, b = blockIdx.x;
    int layer = lr / 3, r = lr % 3;
    int base = bbase[lr * NBUCK + b];
    int next = (b < NBUCK - 1) ? bbase[lr * NBUCK + b + 1] : N_EDGES;
    int cnt = next - base;
    int* reg = pairs + (size_t)lr * N_EDGES + base;
    __shared__ int staged[CAP];
    __shared__ int cnt_l[512];
    __shared__ int keep[BSZ];
    __shared__ int lcur[BSZ];
    int t = threadIdx.x;
    cnt_l[t] = 0; cnt_l[t + 256] = 0;
    __syncthreads();
    for (int i = t; i < cnt; i += 256) {
        int v = reg[i];
        if (i < CAP) staged[i] = v;
        atomicAdd(&cnt_l[v >> 17], 1);
    }
    __syncthreads();
    if (t < 144) keep[t + 256] = cnt_l[t + 256];
    keep[t] = cnt_l[t];
    __syncthreads();
    lds_scan512(cnt_l);
    int d0 = b * BSZ;
    {
        int excl = cnt_l[t] - keep[t];
        lcur[t] = excl;
        start[(size_t)lr * N_NODES + d0 + t] = base + excl;
        deg[(size_t)layer * 6 * N_NODES + (size_t)(3 + r) * N_NODES + d0 + t] = keep[t];
        if (t < 144) {
            int t2 = t + 256;
            int excl2 = cnt_l[t2] - keep[t2];
            lcur[t2] = excl2;
            start[(size_t)lr * N_NODES + d0 + t2] = base + excl2;
            deg[(size_t)layer * 6 * N_NODES + (size_t)(3 + r) * N_NODES + d0 + t2] = keep[t2];
        }
    }
    __syncthreads();
    for (int i = t; i < cnt; i += 256) {
        int v = (i < CAP) ? staged[i] : reg[i];
        int p = atomicAdd(&lcur[v >> 17], 1);
        reg[p] = v & 0x1FFFF;
    }
}

__global__ __launch_bounds__(256) void k_rsqrt(const int* __restrict__ deg,
                                               float* __restrict__ rs) {
    int i = blockIdx.x * 256 + threadIdx.x;
    if (i >= 12 * N_NODES) return;
    int v = deg[i];
    rs[i] = rsqrtf((float)(v < 1 ? 1 : v));
}

// ---------------- x -> fp16 ----------------
__global__ __launch_bounds__(256) void k_cvt_x(const float* __restrict__ x,
                                               _Float16* __restrict__ xh) {
    int i = blockIdx.x * 256 + threadIdx.x;
    if (i >= N_NODES * 64) return;
    float2 v = ((const float2*)x)[i];
    half2v h; h.x = (_Float16)v.x; h.y = (_Float16)v.y;
    ((half2v*)xh)[i] = h;
}

// ---------------- W1/W2 -> fp16 fragment order ----------------
__global__ __launch_bounds__(256) void k_repack(const float* __restrict__ W1,
                                                const float* __restrict__ W2,
                                                _Float16* __restrict__ W1f,
                                                _Float16* __restrict__ W2f) {
    int i = blockIdx.x * 256 + threadIdx.x;
    if (i < 96 * 512) {
        int g = i >> 9, rem = i & 511, L = rem >> 3, j = rem & 7;
        int kc = g >> 3, nt = g & 7;
        int k = kc * 32 + (L >> 4) * 8 + j;
        int n = nt * 16 + (L & 15);
        W1f[i] = (_Float16)W1[k * 128 + n];
    } else if (i < 96 * 512 + 48 * 512) {
        int ii = i - 96 * 512;
        int g = ii >> 9, rem = ii & 511, L = rem >> 3, j = rem & 7;
        int kc = g / 12, nt = g % 12;
        int k = kc * 32 + (L >> 4) * 8 + j;
        int n = nt * 16 + (L & 15);
        int r = n >> 6, c = n & 63;
        W2f[ii] = (_Float16)W2[r * 8192 + k * 64 + c];
    }
}

// ---------------- per-relation gather accumulate (chunked shfl-broadcast, unroll-8) ----------------
__device__ __forceinline__ void accum_rel1(const int* __restrict__ sorted, int j, int n,
                                           const float* __restrict__ rsrow,
                                           const half2v* __restrict__ x2,
                                           int lane, float2& acc) {
    for (int base = 0; base < n; base += 64) {
        int c = n - base; if (c > 64) c = 64;
        int s_l = (lane < c) ? sorted[j + base + lane] : 0;
        float w_l = (lane < c) ? rsrow[s_l] : 0.f;
        int q = 0;
        for (; q + 8 <= c; q += 8) {
            int ss[8]; float ww[8]; half2v vv[8];
#pragma unroll
            for (int u = 0; u < 8; u++) { ss[u] = __shfl(s_l, q + u); ww[u] = __shfl(w_l, q + u); }
#pragma unroll
            for (int u = 0; u < 8; u++) vv[u] = x2[(size_t)ss[u] * 64 + lane];
#pragma unroll
            for (int u = 0; u < 8; u++) {
                acc.x += ww[u] * (float)vv[u].x;
                acc.y += ww[u] * (float)vv[u].y;
            }
        }
        for (; q < c; q++) {
            int s = __shfl(s_l, q); float w = __shfl(w_l, q);
            half2v v = x2[(size_t)s * 64 + lane];
            acc.x += w * (float)v.x; acc.y += w * (float)v.y;
        }
    }
}

// ---------------- layer-1 pull ----------------
__global__ __launch_bounds__(256) void k_pull1(const int* __restrict__ sorted,
                                               const int* __restrict__ start,
                                               const int* __restrict__ deg,
                                               const float* __restrict__ rs,
                                               const _Float16* __restrict__ xh,
                                               _Float16* __restrict__ agg) {
    int wid = threadIdx.x >> 6, lane = threadIdx.x & 63;
    int dst = blockIdx.x * 4 + wid;
    if (dst >= N_NODES) return;
    const half2v* x2 = (const half2v*)xh;
    const int* deg0in = deg + 3 * N_NODES;
    float2 a0 = make_float2(0.f, 0.f), a1 = a0, a2 = a0;
    accum_rel1(sorted, start[dst], deg0in[dst], rs, x2, lane, a0);
    accum_rel1(sorted + N_EDGES, start[N_NODES + dst], deg0in[N_NODES + dst],
               rs + N_NODES, x2, lane, a1);
    accum_rel1(sorted + 2 * N_EDGES, start[2 * N_NODES + dst], deg0in[2 * N_NODES + dst],
               rs + 2 * N_NODES, x2, lane, a2);
    size_t mbase = (size_t)(dst >> 4) * 48 * 128;
    int moff = (dst & 15) * 8;
#pragma unroll
    for (int r = 0; r < 3; r++) {
        float2 a = (r == 0) ? a0 : (r == 1) ? a1 : a2;
        float w = rs[(size_t)(3 + r) * N_NODES + dst];
        int k = r * 128 + 2 * lane;
        size_t idx = mbase + (size_t)(k >> 3) * 128 + moff + (k & 7);
        half2v h; h.x = (_Float16)(a.x * w); h.y = (_Float16)(a.y * w);
        *(half2v*)(agg + idx) = h;
    }
}

// ---------------- fused MFMA GEMM + rs_out(layer1) fold into hW ----------------
__global__ __launch_bounds__(256) void k_gemm12(const _Float16* __restrict__ Af,
                                                const _Float16* __restrict__ W1f,
                                                const float* __restrict__ b1,
                                                const _Float16* __restrict__ W2f,
                                                const float* __restrict__ rs1out,
                                                _Float16* __restrict__ hW) {
    __shared__ _Float16 Hs[4][2048];
    int tid = threadIdx.x;
    int w = tid >> 6, L = tid & 63;
    int mt = blockIdx.x * 4 + w;
    if (mt >= MTILES) return;
    const half8* A8 = (const half8*)Af;
    const half8* B1 = (const half8*)W1f;
    const half8* B2 = (const half8*)W2f;

    floatx4 acc[8];
#pragma unroll
    for (int nt = 0; nt < 8; nt++) acc[nt] = (floatx4)(0.f);
#pragma unroll
    for (int kc = 0; kc < 12; kc++) {
        half8 a = A8[(size_t)mt * 768 + kc * 64 + L];
#pragma unroll
        for (int nt = 0; nt < 8; nt++) {
            half8 b = B1[(kc * 8 + nt) * 64 + L];
            acc[nt] = __builtin_amdgcn_mfma_f32_16x16x32_f16(a, b, acc[nt], 0, 0, 0);
        }
    }
    int cl = L & 15, rw = L >> 4;
#pragma unroll
    for (int nt = 0; nt < 8; nt++) {
        int n = nt * 16 + cl;
        float bs = b1[n] + b1[128 + n] + b1[256 + n];
#pragma unroll
        for (int j = 0; j < 4; j++) {
            int mm = rw * 4 + j;
            float v = acc[nt][j] + bs;
            v = v > 0.f ? v : 0.f;
            Hs[w][(n >> 3) * 128 + mm * 8 + (n & 7)] = (_Float16)v;
        }
    }
    __syncthreads();

    const half8* H8 = (const half8*)(&Hs[w][0]);
    floatx4 acc2[12];
#pragma unroll
    for (int nt = 0; nt < 12; nt++) acc2[nt] = (floatx4)(0.f);
#pragma unroll
    for (int kc = 0; kc < 4; kc++) {
        half8 a = H8[kc * 64 + L];
#pragma unroll
        for (int nt = 0; nt < 12; nt++) {
            half8 b = B2[(kc * 12 + nt) * 64 + L];
            acc2[nt] = __builtin_amdgcn_mfma_f32_16x16x32_f16(a, b, acc2[nt], 0, 0, 0);
        }
    }
#pragma unroll
    for (int j = 0; j < 4; j++) {
        int mm = mt * 16 + rw * 4 + j;
        float wr[3] = {rs1out[mm], rs1out[N_NODES + mm], rs1out[2 * N_NODES + mm]};
#pragma unroll
        for (int nt = 0; nt < 12; nt++) {
            int n = nt * 16 + cl;
            hW[(size_t)mm * 192 + n] = (_Float16)(acc2[nt][j] * wr[nt >> 2]);
        }
    }
}

// ---------------- layer-2 per-relation gather (pre-scaled hW) ----------------
__device__ __forceinline__ void accum_rel2(const int* __restrict__ sorted, int j, int n,
                                           const _Float16* __restrict__ hWr,
                                           int lane, float& acc) {
    for (int base = 0; base < n; base += 64) {
        int c = n - base; if (c > 64) c = 64;
        int s_l = (lane < c) ? sorted[j + base + lane] : 0;
        int q = 0;
        for (; q + 8 <= c; q += 8) {
            int ss[8]; _Float16 vv[8];
#pragma unroll
            for (int u = 0; u < 8; u++) ss[u] = __shfl(s_l, q + u);
#pragma unroll
            for (int u = 0; u < 8; u++) vv[u] = hWr[(size_t)ss[u] * 192 + lane];
#pragma unroll
            for (int u = 0; u < 8; u++) acc += (float)vv[u];
        }
        for (; q < c; q++) {
            int s = __shfl(s_l, q);
            acc += (float)hWr[(size_t)s * 192 + lane];
        }
    }
}

// ---------------- layer-2 pull ----------------
__global__ __launch_bounds__(256) void k_pull2(const int* __restrict__ sorted1,
                                               const int* __restrict__ start1,
                                               const int* __restrict__ deg1,
                                               const float* __restrict__ rs1,
                                               const _Float16* __restrict__ hW,
                                               const float* __restrict__ b2,
                                               float* __restrict__ out) {
    int wid = threadIdx.x >> 6, lane = threadIdx.x & 63;
    int dst = blockIdx.x * 4 + wid;
    if (dst >= N_NODES) return;
    const int* deg1in = deg1 + 3 * N_NODES;
    float a0 = 0.f, a1 = 0.f, a2 = 0.f;
    accum_rel2(sorted1, start1[dst], deg1in[dst], hW, lane, a0);
    accum_rel2(sorted1 + N_EDGES, start1[N_NODES + dst], deg1in[N_NODES + dst],
               hW + 64, lane, a1);
    accum_rel2(sorted1 + 2 * N_EDGES, start1[2 * N_NODES + dst], deg1in[2 * N_NODES + dst],
               hW + 128, lane, a2);
    float o = a0 * rs1[3 * N_NODES + dst] + a1 * rs1[4 * N_NODES + dst] +
              a2 * rs1[5 * N_NODES + dst] + b2[lane] + b2[64 + lane] + b2[128 + lane];
    out[(size_t)dst * 64 + lane] = o;
}

extern "C" void kernel_launch(void* const* d_in, const int* in_sizes, int n_in,
                              void* d_out, int out_size, void* d_ws, size_t ws_size,
                              hipStream_t stream) {
    (void)in_sizes; (void)n_in; (void)out_size; (void)ws_size;
    const float* x  = (const float*)d_in[0];
    const float* W1 = (const float*)d_in[1];
    const float* b1 = (const float*)d_in[2];
    const float* W2 = (const float*)d_in[3];
    const float* b2 = (const float*)d_in[4];
    const int*   ei = (const int*)d_in[5];
    float* out = (float*)d_out;

    char* ws = (char*)d_ws;
    int*      deg     = (int*)(ws + OFF_DEG);
    int*      gcount  = (int*)(ws + OFF_GC);
    int*      bbase   = (int*)(ws + OFF_BB);
    int*      bcursor = (int*)(ws + OFF_BC);
    float*    rs      = (float*)(ws + OFF_RS);
    int*      start   = (int*)(ws + OFF_START);
    int*      pairs   = (int*)(ws + OFF_PAIRS);
    _Float16* xh      = (_Float16*)(ws + OFF_XH);
    _Float16* W1f     = (_Float16*)(ws + OFF_W1F);
    _Float16* W2f     = (_Float16*)(ws + OFF_W2F);
    _Float16* agg     = (_Float16*)(ws + OFF_AGG);
    _Float16* hW      = (_Float16*)(ws + OFF_HW);
    short*    dds     = (short*)(ws + OFF_DDS);
    int*      gcount_s= (int*)(ws + OFF_GCS);
    int*      bbase_s = (int*)(ws + OFF_BBS);
    int*      bcursor_s=(int*)(ws + OFF_BCS);

    hipMemsetAsync(gcount, 0, 6144, stream);
    hipMemsetAsync(gcount_s, 0, 6144, stream);

    k_cvt_x<<<25000, 256, 0, stream>>>(x, xh);
    k_repack<<<288, 256, 0, stream>>>(W1, W2, W1f, W2f);
    k_bhist2<<<dim3(NCHUNK, 6), 256, 0, stream>>>(ei, gcount, gcount_s);
    k_bscan<<<6, 256, 0, stream>>>(gcount, bbase, bcursor);
    k_bscan<<<6, 256, 0, stream>>>(gcount_s, bbase_s, bcursor_s);
    k_bpart<<<dim3(NCHUNK, 6), 256, 0, stream>>>(ei, bcursor, pairs);
    k_bpart_s<<<dim3(NCHUNK, 6), 256, 0, stream>>>(ei, bcursor_s, dds);
    k_bsort<<<dim3(NBUCK, 6), 256, 0, stream>>>(bbase, pairs, start, deg);
    k_bcount_s<<<dim3(NBUCK, 6), 256, 0, stream>>>(bbase_s, dds, deg);
    k_rsqrt<<<4688, 256, 0, stream>>>(deg, rs);
    k_pull1<<<25000, 256, 0, stream>>>(pairs, start, deg, rs, xh, agg);
    k_gemm12<<<(MTILES + 3) / 4, 256, 0, stream>>>(agg, W1f, b1, W2f,
                                                   rs + 6 * (size_t)N_NODES, hW);
    k_pull2<<<25000, 256, 0, stream>>>(pairs + 3 * (size_t)N_EDGES,
                                       start + 3 * (size_t)N_NODES,
                                       deg + 6 * (size_t)N_NODES,
                                       rs + 6 * (size_t)N_NODES,
                                       hW, b2, out);
}

// Round 7
// 769.153 us; speedup vs baseline: 17.1428x; 1.0138x over previous
//
#include <hip/hip_runtime.h>

#define N_NODES 100000
#define N_EDGES 1600000
#define NBUCK 250          // buckets per (layer,rel)
#define BSZ 400            // nodes per bucket (250*400 = 100000)
#define CHUNK 8192         // edges per partition block
#define NCHUNK 196         // ceil(E/CHUNK)
#define CAP 8192           // LDS staging capacity in k_bsort
#define MTILES 6250        // N_NODES / 16
#define NTILE 13           // src tiles of 8192 rows (100000 >> 13 -> 0..12)
#define NKEY (BSZ * NTILE) // 5200 sort bins
#define NKEYP 5376         // padded to 21*256

typedef _Float16 half8 __attribute__((ext_vector_type(8)));
typedef _Float16 half2v __attribute__((ext_vector_type(2)));
typedef float floatx4 __attribute__((ext_vector_type(4)));

// workspace layout (bytes), total ~191.4 MB:
#define OFF_DEG   0ull           // 12N int: per layer, out r0..2 then in r0..2
#define OFF_GC    4800000ull     // 1500 int (pad 6144) dst-bucket counts
#define OFF_BB    4806144ull     // dst bucket bases
#define OFF_BC    4812288ull     // dst bucket cursors
#define OFF_RS    4818432ull     // 12N float
#define OFF_START 9618432ull     // 6N int
#define OFF_PAIRS 12018432ull    // 6E int
#define OFF_XH    50418432ull    // N*128 fp16 (row-major)
#define OFF_W1F   76018432ull    // 96*512 fp16 (frag order)
#define OFF_W2F   76116736ull    // 48*512 fp16 (frag order)
#define OFF_AGG   76165888ull    // N*384 fp16, A-frag layout; head reused as src-count scratch
#define OFF_HW    152965888ull   // N*192 fp16, row-major (pre-scaled by rs_out layer1)

// src-counting scratch aliased into agg region (dead until k_pull1):
#define OFF_DDS   OFF_AGG                    // 6E short = 19.2 MB
#define OFF_GCS   (OFF_AGG + 19200000ull)    // 1500 int (pad 6144)
#define OFF_BBS   (OFF_AGG + 19206144ull)    // 1500 int
#define OFF_BCS   (OFF_AGG + 19212288ull)    // 1500 int

__device__ __forceinline__ void lds_scan256(int* a) {
    int t = threadIdx.x;
    for (int off = 1; off < 256; off <<= 1) {
        int v = (t >= off) ? a[t - off] : 0;
        __syncthreads();
        a[t] += v;
        __syncthreads();
    }
}

// ---------------- fused bucket histograms of src AND dst ----------------
__global__ __launch_bounds__(256) void k_bhist2(const int* __restrict__ ei,
                                                int* __restrict__ gcount_d,
                                                int* __restrict__ gcount_s) {
    int lr = blockIdx.y;
    int e0 = blockIdx.x * CHUNK;
    int n = min(CHUNK, N_EDGES - e0);
    const int* bs = ei + (size_t)lr * 2 * N_EDGES + e0;
    const int* bd = bs + N_EDGES;
    __shared__ int lhs[256];
    __shared__ int lhd[256];
    int t = threadIdx.x;
    lhs[t] = 0; lhd[t] = 0;
    __syncthreads();
    for (int i = t; i < n; i += 256) {
        atomicAdd(&lhs[bs[i] / BSZ], 1);
        atomicAdd(&lhd[bd[i] / BSZ], 1);
    }
    __syncthreads();
    if (t < NBUCK) {
        if (lhd[t]) atomicAdd(&gcount_d[lr * NBUCK + t], lhd[t]);
        if (lhs[t]) atomicAdd(&gcount_s[lr * NBUCK + t], lhs[t]);
    }
}

// ---------------- scan bucket counts ----------------
__global__ __launch_bounds__(256) void k_bscan(const int* __restrict__ gcount,
                                               int* __restrict__ bbase,
                                               int* __restrict__ bcursor) {
    int lr = blockIdx.x, t = threadIdx.x;
    __shared__ int a[256];
    int v = (t < NBUCK) ? gcount[lr * NBUCK + t] : 0;
    a[t] = v;
    __syncthreads();
    lds_scan256(a);
    if (t < NBUCK) {
        int excl = a[t] - v;
        bbase[lr * NBUCK + t] = excl;
        bcursor[lr * NBUCK + t] = excl;
    }
}

// ---------------- partition edges into dst buckets (payload src|dd<<17) ----------------
__global__ __launch_bounds__(256) void k_bpart(const int* __restrict__ ei,
                                               int* __restrict__ bcursor,
                                               int* __restrict__ pairs) {
    int lr = blockIdx.y;
    int e0 = blockIdx.x * CHUNK;
    int n = min(CHUNK, N_EDGES - e0);
    const int* bs = ei + (size_t)lr * 2 * N_EDGES + e0;
    const int* bd = bs + N_EDGES;
    __shared__ int lh[256];
    __shared__ int lexcl[256];
    __shared__ int lcur[256];
    __shared__ int gb[256];
    __shared__ int staged[CHUNK];
    __shared__ unsigned char stb[CHUNK];
    int t = threadIdx.x;
    lh[t] = 0;
    __syncthreads();
    for (int i = t; i < n; i += 256)
        atomicAdd(&lh[bd[i] / BSZ], 1);
    __syncthreads();
    int cnt_t = lh[t];
    __syncthreads();
    lds_scan256(lh);
    int excl_t = lh[t] - cnt_t;
    lexcl[t] = excl_t;
    lcur[t] = excl_t;
    if (t < NBUCK) gb[t] = cnt_t ? atomicAdd(&bcursor[lr * NBUCK + t], cnt_t) : 0;
    __syncthreads();
    for (int i = t; i < n; i += 256) {
        int s = bs[i], d = bd[i];
        int b = d / BSZ;
        int dd = d - b * BSZ;
        int p = atomicAdd(&lcur[b], 1);
        staged[p] = s | (dd << 17);
        stb[p] = (unsigned char)b;
    }
    __syncthreads();
    int* outp = pairs + (size_t)lr * N_EDGES;
    for (int i = t; i < n; i += 256) {
        int b = stb[i];
        outp[gb[b] + (i - lexcl[b])] = staged[i];
    }
}

// ---------------- partition src into buckets (payload = 9-bit in-bucket offset) ----------------
__global__ __launch_bounds__(256) void k_bpart_s(const int* __restrict__ ei,
                                                 int* __restrict__ bcursor_s,
                                                 short* __restrict__ dds) {
    int lr = blockIdx.y;
    int e0 = blockIdx.x * CHUNK;
    int n = min(CHUNK, N_EDGES - e0);
    const int* bs = ei + (size_t)lr * 2 * N_EDGES + e0;
    __shared__ int lh[256];
    __shared__ int lexcl[256];
    __shared__ int lcur[256];
    __shared__ int gb[256];
    __shared__ short staged[CHUNK];
    __shared__ unsigned char stb[CHUNK];
    int t = threadIdx.x;
    lh[t] = 0;
    __syncthreads();
    for (int i = t; i < n; i += 256)
        atomicAdd(&lh[bs[i] / BSZ], 1);
    __syncthreads();
    int cnt_t = lh[t];
    __syncthreads();
    lds_scan256(lh);
    int excl_t = lh[t] - cnt_t;
    lexcl[t] = excl_t;
    lcur[t] = excl_t;
    if (t < NBUCK) gb[t] = cnt_t ? atomicAdd(&bcursor_s[lr * NBUCK + t], cnt_t) : 0;
    __syncthreads();
    for (int i = t; i < n; i += 256) {
        int s = bs[i];
        int b = s / BSZ;
        int p = atomicAdd(&lcur[b], 1);
        staged[p] = (short)(s - b * BSZ);
        stb[p] = (unsigned char)b;
    }
    __syncthreads();
    short* outp = dds + (size_t)lr * N_EDGES;
    for (int i = t; i < n; i += 256) {
        int b = stb[i];
        outp[gb[b] + (i - lexcl[b])] = staged[i];
    }
}

// ---------------- per-bucket src count -> out-degree (coalesced, no global atomics) ----------------
__global__ __launch_bounds__(256) void k_bcount_s(const int* __restrict__ bbase_s,
                                                  const short* __restrict__ dds,
                                                  int* __restrict__ deg) {
    int lr = blockIdx.y, b = blockIdx.x;
    int layer = lr / 3, r = lr % 3;
    int base = bbase_s[lr * NBUCK + b];
    int next = (b < NBUCK - 1) ? bbase_s[lr * NBUCK + b + 1] : N_EDGES;
    int cnt = next - base;
    const short* reg = dds + (size_t)lr * N_EDGES + base;
    __shared__ int h[BSZ];
    int t = threadIdx.x;
    h[t] = 0;
    if (t < BSZ - 256) h[t + 256] = 0;
    __syncthreads();
    for (int i = t; i < cnt; i += 256)
        atomicAdd(&h[reg[i]], 1);
    __syncthreads();
    int* degout = deg + (size_t)layer * 6 * N_NODES + (size_t)r * N_NODES + b * BSZ;
    degout[t] = h[t];
    if (t < BSZ - 256) degout[t + 256] = h[t + 256];
}

// ---------------- per-bucket counting sort by (dd, src-tile) + CSR + in-degree ----------------
__global__ __launch_bounds__(256) void k_bsort(const int* __restrict__ bbase,
                                               int* __restrict__ pairs,
                                               int* __restrict__ start,
                                               int* __restrict__ deg) {
    int lr = blockIdx.y, b = blockIdx.x;
    int layer = lr / 3, r = lr % 3;
    int base = bbase[lr * NBUCK + b];
    int next = (b < NBUCK - 1) ? bbase[lr * NBUCK + b + 1] : N_EDGES;
    int cnt = next - base;
    int* reg = pairs + (size_t)lr * N_EDGES + base;
    __shared__ int staged[CAP];      // 32 KB
    __shared__ int hist[NKEYP];      // 21.5 KB: counts -> exclusive starts -> cursors
    __shared__ int tsum[256];
    int t = threadIdx.x;
    for (int i = t; i < NKEYP; i += 256) hist[i] = 0;
    __syncthreads();
    for (int i = t; i < cnt; i += 256) {
        int v = reg[i];
        if (i < CAP) staged[i] = v;
        int key = (v >> 17) * NTILE + ((v & 0x1FFFF) >> 13);
        atomicAdd(&hist[key], 1);
    }
    __syncthreads();
    // scan 5376 bins: thread t owns bins [t*21, t*21+21)
    int b0 = t * 21;
    int loc[21];
    int s = 0;
#pragma unroll
    for (int k = 0; k < 21; k++) { loc[k] = s; s += hist[b0 + k]; }
    tsum[t] = s;
    __syncthreads();
    lds_scan256(tsum);               // inclusive
    int tbase = tsum[t] - s;
#pragma unroll
    for (int k = 0; k < 21; k++) hist[b0 + k] = tbase + loc[k];
    __syncthreads();
    // CSR start + in-degree from bin boundaries (hist[5200] == cnt via zero pad)
    int d0 = b * BSZ;
    {
        int st = hist[t * NTILE];
        int en = hist[(t + 1) * NTILE];
        start[(size_t)lr * N_NODES + d0 + t] = base + st;
        deg[(size_t)layer * 6 * N_NODES + (size_t)(3 + r) * N_NODES + d0 + t] = en - st;
        if (t < BSZ - 256) {
            int t2 = t + 256;
            int st2 = hist[t2 * NTILE];
            int en2 = hist[(t2 + 1) * NTILE];
            start[(size_t)lr * N_NODES + d0 + t2] = base + st2;
            deg[(size_t)layer * 6 * N_NODES + (size_t)(3 + r) * N_NODES + d0 + t2] = en2 - st2;
        }
    }
    __syncthreads();
    // scatter (hist becomes cursors)
    for (int i = t; i < cnt; i += 256) {
        int v = (i < CAP) ? staged[i] : reg[i];
        int key = (v >> 17) * NTILE + ((v & 0x1FFFF) >> 13);
        int p = atomicAdd(&hist[key], 1);
        reg[p] = v & 0x1FFFF;
    }
}

__global__ __launch_bounds__(256) void k_rsqrt(const int* __restrict__ deg,
                                               float* __restrict__ rs) {
    int i = blockIdx.x * 256 + threadIdx.x;
    if (i >= 12 * N_NODES) return;
    int v = deg[i];
    rs[i] = rsqrtf((float)(v < 1 ? 1 : v));
}

// ---------------- x -> fp16 ----------------
__global__ __launch_bounds__(256) void k_cvt_x(const float* __restrict__ x,
                                               _Float16* __restrict__ xh) {
    int i = blockIdx.x * 256 + threadIdx.x;
    if (i >= N_NODES * 64) return;
    float2 v = ((const float2*)x)[i];
    half2v h; h.x = (_Float16)v.x; h.y = (_Float16)v.y;
    ((half2v*)xh)[i] = h;
}

// ---------------- W1/W2 -> fp16 fragment order ----------------
__global__ __launch_bounds__(256) void k_repack(const float* __restrict__ W1,
                                                const float* __restrict__ W2,
                                                _Float16* __restrict__ W1f,
                                                _Float16* __restrict__ W2f) {
    int i = blockIdx.x * 256 + threadIdx.x;
    if (i < 96 * 512) {
        int g = i >> 9, rem = i & 511, L = rem >> 3, j = rem & 7;
        int kc = g >> 3, nt = g & 7;
        int k = kc * 32 + (L >> 4) * 8 + j;
        int n = nt * 16 + (L & 15);
        W1f[i] = (_Float16)W1[k * 128 + n];
    } else if (i < 96 * 512 + 48 * 512) {
        int ii = i - 96 * 512;
        int g = ii >> 9, rem = ii & 511, L = rem >> 3, j = rem & 7;
        int kc = g / 12, nt = g % 12;
        int k = kc * 32 + (L >> 4) * 8 + j;
        int n = nt * 16 + (L & 15);
        int r = n >> 6, c = n & 63;
        W2f[ii] = (_Float16)W2[r * 8192 + k * 64 + c];
    }
}

// ---------------- per-relation gather accumulate (chunked shfl-broadcast, unroll-8) ----------------
__device__ __forceinline__ void accum_rel1(const int* __restrict__ sorted, int j, int n,
                                           const float* __restrict__ rsrow,
                                           const half2v* __restrict__ x2,
                                           int lane, float2& acc) {
    for (int base = 0; base < n; base += 64) {
        int c = n - base; if (c > 64) c = 64;
        int s_l = (lane < c) ? sorted[j + base + lane] : 0;
        float w_l = (lane < c) ? rsrow[s_l] : 0.f;
        int q = 0;
        for (; q + 8 <= c; q += 8) {
            int ss[8]; float ww[8]; half2v vv[8];
#pragma unroll
            for (int u = 0; u < 8; u++) { ss[u] = __shfl(s_l, q + u); ww[u] = __shfl(w_l, q + u); }
#pragma unroll
            for (int u = 0; u < 8; u++) vv[u] = x2[(size_t)ss[u] * 64 + lane];
#pragma unroll
            for (int u = 0; u < 8; u++) {
                acc.x += ww[u] * (float)vv[u].x;
                acc.y += ww[u] * (float)vv[u].y;
            }
        }
        for (; q < c; q++) {
            int s = __shfl(s_l, q); float w = __shfl(w_l, q);
            half2v v = x2[(size_t)s * 64 + lane];
            acc.x += w * (float)v.x; acc.y += w * (float)v.y;
        }
    }
}

// ---------------- layer-1 pull ----------------
__global__ __launch_bounds__(256) void k_pull1(const int* __restrict__ sorted,
                                               const int* __restrict__ start,
                                               const int* __restrict__ deg,
                                               const float* __restrict__ rs,
                                               const _Float16* __restrict__ xh,
                                               _Float16* __restrict__ agg) {
    int wid = threadIdx.x >> 6, lane = threadIdx.x & 63;
    int dst = blockIdx.x * 4 + wid;
    if (dst >= N_NODES) return;
    const half2v* x2 = (const half2v*)xh;
    const int* deg0in = deg + 3 * N_NODES;
    float2 a0 = make_float2(0.f, 0.f), a1 = a0, a2 = a0;
    accum_rel1(sorted, start[dst], deg0in[dst], rs, x2, lane, a0);
    accum_rel1(sorted + N_EDGES, start[N_NODES + dst], deg0in[N_NODES + dst],
               rs + N_NODES, x2, lane, a1);
    accum_rel1(sorted + 2 * N_EDGES, start[2 * N_NODES + dst], deg0in[2 * N_NODES + dst],
               rs + 2 * N_NODES, x2, lane, a2);
    size_t mbase = (size_t)(dst >> 4) * 48 * 128;
    int moff = (dst & 15) * 8;
#pragma unroll
    for (int r = 0; r < 3; r++) {
        float2 a = (r == 0) ? a0 : (r == 1) ? a1 : a2;
        float w = rs[(size_t)(3 + r) * N_NODES + dst];
        int k = r * 128 + 2 * lane;
        size_t idx = mbase + (size_t)(k >> 3) * 128 + moff + (k & 7);
        half2v h; h.x = (_Float16)(a.x * w); h.y = (_Float16)(a.y * w);
        *(half2v*)(agg + idx) = h;
    }
}

// ---------------- fused MFMA GEMM + rs_out(layer1) fold into hW ----------------
__global__ __launch_bounds__(256) void k_gemm12(const _Float16* __restrict__ Af,
                                                const _Float16* __restrict__ W1f,
                                                const float* __restrict__ b1,
                                                const _Float16* __restrict__ W2f,
                                                const float* __restrict__ rs1out,
                                                _Float16* __restrict__ hW) {
    __shared__ _Float16 Hs[4][2048];
    int tid = threadIdx.x;
    int w = tid >> 6, L = tid & 63;
    int mt = blockIdx.x * 4 + w;
    if (mt >= MTILES) return;
    const half8* A8 = (const half8*)Af;
    const half8* B1 = (const half8*)W1f;
    const half8* B2 = (const half8*)W2f;

    floatx4 acc[8];
#pragma unroll
    for (int nt = 0; nt < 8; nt++) acc[nt] = (floatx4)(0.f);
#pragma unroll
    for (int kc = 0; kc < 12; kc++) {
        half8 a = A8[(size_t)mt * 768 + kc * 64 + L];
#pragma unroll
        for (int nt = 0; nt < 8; nt++) {
            half8 b = B1[(kc * 8 + nt) * 64 + L];
            acc[nt] = __builtin_amdgcn_mfma_f32_16x16x32_f16(a, b, acc[nt], 0, 0, 0);
        }
    }
    int cl = L & 15, rw = L >> 4;
#pragma unroll
    for (int nt = 0; nt < 8; nt++) {
        int n = nt * 16 + cl;
        float bs = b1[n] + b1[128 + n] + b1[256 + n];
#pragma unroll
        for (int j = 0; j < 4; j++) {
            int mm = rw * 4 + j;
            float v = acc[nt][j] + bs;
            v = v > 0.f ? v : 0.f;
            Hs[w][(n >> 3) * 128 + mm * 8 + (n & 7)] = (_Float16)v;
        }
    }
    __syncthreads();

    const half8* H8 = (const half8*)(&Hs[w][0]);
    floatx4 acc2[12];
#pragma unroll
    for (int nt = 0; nt < 12; nt++) acc2[nt] = (floatx4)(0.f);
#pragma unroll
    for (int kc = 0; kc < 4; kc++) {
        half8 a = H8[kc * 64 + L];
#pragma unroll
        for (int nt = 0; nt < 12; nt++) {
            half8 b = B2[(kc * 12 + nt) * 64 + L];
            acc2[nt] = __builtin_amdgcn_mfma_f32_16x16x32_f16(a, b, acc2[nt], 0, 0, 0);
        }
    }
#pragma unroll
    for (int j = 0; j < 4; j++) {
        int mm = mt * 16 + rw * 4 + j;
        float wr[3] = {rs1out[mm], rs1out[N_NODES + mm], rs1out[2 * N_NODES + mm]};
#pragma unroll
        for (int nt = 0; nt < 12; nt++) {
            int n = nt * 16 + cl;
            hW[(size_t)mm * 192 + n] = (_Float16)(acc2[nt][j] * wr[nt >> 2]);
        }
    }
}

// ---------------- layer-2 per-relation gather (pre-scaled hW) ----------------
__device__ __forceinline__ void accum_rel2(const int* __restrict__ sorted, int j, int n,
                                           const _Float16* __restrict__ hWr,
                                           int lane, float& acc) {
    for (int base = 0; base < n; base += 64) {
        int c = n - base; if (c > 64) c = 64;
        int s_l = (lane < c) ? sorted[j + base + lane] : 0;
        int q = 0;
        for (; q + 8 <= c; q += 8) {
            int ss[8]; _Float16 vv[8];
#pragma unroll
            for (int u = 0; u < 8; u++) ss[u] = __shfl(s_l, q + u);
#pragma unroll
            for (int u = 0; u < 8; u++) vv[u] = hWr[(size_t)ss[u] * 192 + lane];
#pragma unroll
            for (int u = 0; u < 8; u++) acc += (float)vv[u];
        }
        for (; q < c; q++) {
            int s = __shfl(s_l, q);
            acc += (float)hWr[(size_t)s * 192 + lane];
        }
    }
}

// ---------------- layer-2 pull ----------------
__global__ __launch_bounds__(256) void k_pull2(const int* __restrict__ sorted1,
                                               const int* __restrict__ start1,
                                               const int* __restrict__ deg1,
                                               const float* __restrict__ rs1,
                                               const _Float16* __restrict__ hW,
                                               const float* __restrict__ b2,
                                               float* __restrict__ out) {
    int wid = threadIdx.x >> 6, lane = threadIdx.x & 63;
    int dst = blockIdx.x * 4 + wid;
    if (dst >= N_NODES) return;
    const int* deg1in = deg1 + 3 * N_NODES;
    float a0 = 0.f, a1 = 0.f, a2 = 0.f;
    accum_rel2(sorted1, start1[dst], deg1in[dst], hW, lane, a0);
    accum_rel2(sorted1 + N_EDGES, start1[N_NODES + dst], deg1in[N_NODES + dst],
               hW + 64, lane, a1);
    accum_rel2(sorted1 + 2 * N_EDGES, start1[2 * N_NODES + dst], deg1in[2 * N_NODES + dst],
               hW + 128, lane, a2);
    float o = a0 * rs1[3 * N_NODES + dst] + a1 * rs1[4 * N_NODES + dst] +
              a2 * rs1[5 * N_NODES + dst] + b2[lane] + b2[64 + lane] + b2[128 + lane];
    out[(size_t)dst * 64 + lane] = o;
}

extern "C" void kernel_launch(void* const* d_in, const int* in_sizes, int n_in,
                              void* d_out, int out_size, void* d_ws, size_t ws_size,
                              hipStream_t stream) {
    (void)in_sizes; (void)n_in; (void)out_size; (void)ws_size;
    const float* x  = (const float*)d_in[0];
    const float* W1 = (const float*)d_in[1];
    const float* b1 = (const float*)d_in[2];
    const float* W2 = (const float*)d_in[3];
    const float* b2 = (const float*)d_in[4];
    const int*   ei = (const int*)d_in[5];
    float* out = (float*)d_out;

    char* ws = (char*)d_ws;
    int*      deg     = (int*)(ws + OFF_DEG);
    int*      gcount  = (int*)(ws + OFF_GC);
    int*      bbase   = (int*)(ws + OFF_BB);
    int*      bcursor = (int*)(ws + OFF_BC);
    float*    rs      = (float*)(ws + OFF_RS);
    int*      start   = (int*)(ws + OFF_START);
    int*      pairs   = (int*)(ws + OFF_PAIRS);
    _Float16* xh      = (_Float16*)(ws + OFF_XH);
    _Float16* W1f     = (_Float16*)(ws + OFF_W1F);
    _Float16* W2f     = (_Float16*)(ws + OFF_W2F);
    _Float16* agg     = (_Float16*)(ws + OFF_AGG);
    _Float16* hW      = (_Float16*)(ws + OFF_HW);
    short*    dds     = (short*)(ws + OFF_DDS);
    int*      gcount_s= (int*)(ws + OFF_GCS);
    int*      bbase_s = (int*)(ws + OFF_BBS);
    int*      bcursor_s=(int*)(ws + OFF_BCS);

    hipMemsetAsync(gcount, 0, 6144, stream);
    hipMemsetAsync(gcount_s, 0, 6144, stream);

    k_cvt_x<<<25000, 256, 0, stream>>>(x, xh);
    k_repack<<<288, 256, 0, stream>>>(W1, W2, W1f, W2f);
    k_bhist2<<<dim3(NCHUNK, 6), 256, 0, stream>>>(ei, gcount, gcount_s);
    k_bscan<<<6, 256, 0, stream>>>(gcount, bbase, bcursor);
    k_bscan<<<6, 256, 0, stream>>>(gcount_s, bbase_s, bcursor_s);
    k_bpart<<<dim3(NCHUNK, 6), 256, 0, stream>>>(ei, bcursor, pairs);
    k_bpart_s<<<dim3(NCHUNK, 6), 256, 0, stream>>>(ei, bcursor_s, dds);
    k_bsort<<<dim3(NBUCK, 6), 256, 0, stream>>>(bbase, pairs, start, deg);
    k_bcount_s<<<dim3(NBUCK, 6), 256, 0, stream>>>(bbase_s, dds, deg);
    k_rsqrt<<<4688, 256, 0, stream>>>(deg, rs);
    k_pull1<<<25000, 256, 0, stream>>>(pairs, start, deg, rs, xh, agg);
    k_gemm12<<<(MTILES + 3) / 4, 256, 0, stream>>>(agg, W1f, b1, W2f,
                                                   rs + 6 * (size_t)N_NODES, hW);
    k_pull2<<<25000, 256, 0, stream>>>(pairs + 3 * (size_t)N_EDGES,
                                       start + 3 * (size_t)N_NODES,
                                       deg + 6 * (size_t)N_NODES,
                                       rs + 6 * (size_t)N_NODES,
                                       hW, b2, out);
}